// Round 2
// baseline (359.722 us; speedup 1.0000x reference)
//
#include <hip/hip_runtime.h>
#include <hip/hip_bf16.h>
#include <hip/hip_cooperative_groups.h>

#define DEV __device__ __forceinline__

typedef __attribute__((ext_vector_type(8))) short bf16x8;
typedef __attribute__((ext_vector_type(4))) float f32x4;

// N=65536 tokens, 8 heads, head dim 32, feature dim 256, block 256
static constexpr float QSCALE = 0.17677669529663687f; // 1/sqrt(32)
static constexpr float LOG2E  = 1.4426950408889634f;

DEV unsigned short f2bf(float f) {
    union { float f; unsigned int u; } a; a.f = f;
    unsigned int r = (a.u + 0x7fffu + ((a.u >> 16) & 1u)) >> 16; // RNE
    return (unsigned short)r;
}
DEV unsigned int pack2bf(float lo, float hi) {   // v_cvt_pk_bf16_f32 on gfx950
    float2 t; t.x = lo; t.y = hi;
    __hip_bfloat162 h = __float22bfloat162_rn(t);
    unsigned int u; __builtin_memcpy(&u, &h, 4);
    return u;
}
DEV int bucketof(float v) {
    int b = (int)(v * 65536.0f);
    b = b < 0 ? 0 : b;
    b = b > 65535 ? 65535 : b;
    return b;
}

// ---------------- fused pre-chain: weight prep + stable argsort of coords[:,0]
// One cooperative kernel (256 blocks x 256 threads, co-resident) replaces
// memset + khist + kscan1/2/3 + kscatter + krank + kwprep = 8 dispatches.
// Each inter-dispatch boundary cost ~10 us of launch/serialization overhead
// (~80 us total, the dominant pipeline cost per the R1 profile); grid.sync()
// phases cost ~2-4 us each instead.
__global__ __launch_bounds__(256) void ksortprep(
    const float* __restrict__ coords,
    const float* __restrict__ wq, const float* __restrict__ wk,
    const float* __restrict__ wv, const float* __restrict__ w_out,
    const float* __restrict__ ff1, const float* __restrict__ ff2,
    const float* __restrict__ w_rpe,
    unsigned int* hist, unsigned int* excl, unsigned int* aux,
    unsigned int* memb, unsigned int* order,
    unsigned short* wqkvb, unsigned short* woutb,
    unsigned short* ff1b, unsigned short* ff2b, float* w2)
{
    cooperative_groups::grid_group grid = cooperative_groups::this_grid();
    __shared__ unsigned int s[256];
    __shared__ float part[4];
    int tid = threadIdx.x;
    int g = blockIdx.x * 256 + tid;

    // ---- phase 0: zero hist + weight bf16 conversion + w2 reduction ----
    hist[g] = 0u;
    if (g < 34816) {
        int i = g;
        if (i < 8192)        wqkvb[i] = f2bf(wq[i] * (QSCALE * LOG2E));
        else if (i < 16384)  wqkvb[i] = f2bf(wk[i - 8192]);
        else if (i < 24576)  wqkvb[i] = f2bf(wv[i - 16384]);
        else if (i < 32768)  woutb[i - 24576] = f2bf(w_out[i - 24576]);
        else if (i < 33792)  ff1b[i - 32768] = f2bf(ff1[i - 32768]);
        else                 ff2b[i - 33792] = f2bf(ff2[i - 33792]);
    }
    if (blockIdx.x >= 240) {               // 16 blocks: w2[p], p = h*2 + c
        int p = blockIdx.x - 240;
        int h = p >> 1, c = p & 1;
        int d = tid >> 3, j = tid & 7;
        float v = w_rpe[(h * 32 + d) * 16 + c * 8 + j];
        float v2 = v * v;
        for (int m = 32; m >= 1; m >>= 1) v2 += __shfl_xor(v2, m);
        if ((tid & 63) == 0) part[tid >> 6] = v2;
        __syncthreads();
        if (tid == 0) w2[p] = (part[0] + part[1] + part[2] + part[3]) * (1.0f / 256.0f) * LOG2E;
    }
    int myb = bucketof(coords[g * 3]);
    unsigned int ki = __float_as_uint(coords[g * 3]);
    grid.sync();

    // ---- phase 1: histogram ----
    atomicAdd(&hist[myb], 1u);
    grid.sync();

    // ---- phase 2: per-block inclusive scan -> local exclusive + block totals ----
    unsigned int v = hist[g];
    s[tid] = v; __syncthreads();
    for (int off = 1; off < 256; off <<= 1) {
        unsigned int t = (tid >= off) ? s[tid - off] : 0u;
        __syncthreads();
        s[tid] += t;
        __syncthreads();
    }
    unsigned int lexcl = s[tid] - v;
    if (tid == 255) aux[blockIdx.x] = s[255];
    grid.sync();

    // ---- phase 3: scan the 256 block totals (block 0 only) ----
    if (blockIdx.x == 0) {
        unsigned int av = aux[tid];
        s[tid] = av; __syncthreads();
        for (int off = 1; off < 256; off <<= 1) {
            unsigned int t = (tid >= off) ? s[tid - off] : 0u;
            __syncthreads();
            s[tid] += t;
            __syncthreads();
        }
        aux[tid] = s[tid] - av;
    }
    grid.sync();

    // ---- phase 4: global exclusive offsets ----
    excl[g] = lexcl + aux[blockIdx.x];
    grid.sync();

    // ---- phase 5: scatter (excl[b] becomes inclusive end after all adds) ----
    unsigned int pos = atomicAdd(&excl[myb], 1u);
    memb[pos] = (unsigned int)g;
    grid.sync();

    // ---- phase 6: stable rank within bucket -> order ----
    unsigned int st = (myb == 0) ? 0u : excl[myb - 1];
    unsigned int end = excl[myb];
    unsigned int r = st;
    for (unsigned int s2 = st; s2 < end; ++s2) {
        unsigned int j = memb[s2];
        unsigned int kj = __float_as_uint(coords[j * 3]);
        if (kj < ki || (kj == ki && j < (unsigned int)g)) r++;
    }
    order[r] = (unsigned int)g;
}

// ---------------- fully fused: LN1 + QKV + attention(8 heads) + out-proj +
// residual + LN2 + FFN + residual, per (bucket, query-half) block ----------------
// Grid 512 = 256 buckets x 2 query-halves, 256 threads (4 waves), 2 blocks/CU.
// Out-proj decomposes per head: aggr += O_h @ w_out_h^T accumulated in f32 MFMA
// accumulators across a rolled 8-head loop. K/V generated for all 256 tokens per
// block (x2 duplication across halves); Q only for the 128 owned rows.
// Bias head-independent on the K side: keext = [a, b, a^2, b^2], query side
// carries [2w0 a_i, 2w1 b_i, -w0, -w1].
// Block swizzle: both halves of a bucket share blockIdx%8 -> same XCD L2.
// LDS: xnb 16384 + Qb 8192 + Kb 20480 + Vt 16896 + kext 2048 + pf 2048
//      + Pst 9216 = 75264 B -> 2 blocks/CU.
__global__ __launch_bounds__(256, 2) void kattn(
    const float* __restrict__ x, const float* __restrict__ g1, const float* __restrict__ be1,
    const unsigned short* __restrict__ wqkvb,
    const unsigned int* __restrict__ order, const float* __restrict__ coords,
    const float* __restrict__ w2,
    const unsigned short* __restrict__ woutb, const float* __restrict__ b_out,
    const float* __restrict__ g2, const float* __restrict__ be2,
    const unsigned short* __restrict__ ff1b, const float* __restrict__ ffb1,
    const unsigned short* __restrict__ ff2b, const float* __restrict__ ffb2,
    float* __restrict__ out)
{
    __shared__ unsigned short xnb[256][32];     // 16384 B  LN'd x, swizzled chunks
    __shared__ unsigned short Qb[128][32];      //  8192 B  this half's Q, swizzled
    __shared__ unsigned short Kb[256][40];      // 20480 B  padded (conflict-free)
    __shared__ unsigned short Vt[32][264];      // 16896 B  [feature][permuted token]
    __shared__ unsigned short kext[256][4];     //  2048 B  {a, b, a^2, b^2} bf16
    __shared__ float2 pf[256];                  //  2048 B  f32 coords for Q side
    __shared__ unsigned short Pst[4][16][72];   //  9216 B  per-wave strip staging

    int bh = blockIdx.x;
    int b = (bh & 7) * 32 + ((bh >> 3) & 31);   // bucket; both halves share bh%8 (XCD)
    int qbase = (bh >> 8) * 128;                // query-row window base (0 or 128)
    int tid = threadIdx.x, wave = tid >> 6, lane = tid & 63;
    int col = lane & 15, quad = lane >> 4;

    // ---- stage A: gather x row, LN1 -> xnb (swizzled); coords -> kext/pf ----
    {
        int t = tid;
        int tok = (int)order[b * 256 + t];
        float a = coords[tok * 3 + 1], bb = coords[tok * 3 + 2];
        pf[t] = make_float2(a, bb);
        uint2 kv;
        kv.x = pack2bf(a, bb);
        kv.y = pack2bf(a * a, bb * bb);
        *(uint2*)&kext[t][0] = kv;

        float xv[32];
        const float4* xr = (const float4*)(x + (size_t)tok * 32);
#pragma unroll
        for (int q4 = 0; q4 < 8; q4++) {
            float4 v4 = xr[q4];
            xv[q4 * 4 + 0] = v4.x; xv[q4 * 4 + 1] = v4.y; xv[q4 * 4 + 2] = v4.z; xv[q4 * 4 + 3] = v4.w;
        }
        float mu = 0.f;
#pragma unroll
        for (int d = 0; d < 32; d++) mu += xv[d];
        mu *= (1.0f / 32.0f);
        float var = 0.f;
#pragma unroll
        for (int d = 0; d < 32; d++) { float c = xv[d] - mu; var += c * c; }
        var *= (1.0f / 32.0f);
        float rstd = rsqrtf(var + 1e-5f);
        unsigned int pk[16];
#pragma unroll
        for (int w = 0; w < 16; w++) {
            float a2 = (xv[2 * w] - mu) * rstd * g1[2 * w] + be1[2 * w];
            float b2 = (xv[2 * w + 1] - mu) * rstd * g1[2 * w + 1] + be1[2 * w + 1];
            pk[w] = pack2bf(a2, b2);
        }
        int v = (t >> 1) & 3;                    // chunk swizzle key
        uint4* dst = (uint4*)&xnb[t][0];
#pragma unroll
        for (int w4 = 0; w4 < 4; w4++) {
            uint4 v4; v4.x = pk[w4*4]; v4.y = pk[w4*4+1]; v4.z = pk[w4*4+2]; v4.w = pk[w4*4+3];
            dst[w4 ^ v] = v4;                    // logical chunk w4 -> physical w4^v
        }
    }
    __syncthreads();

    // extended-K fragments: head-independent {a, b, a^2, b^2} -> hoist once
    bf16x8 keext[16];
#pragma unroll
    for (int nt = 0; nt < 16; nt++) {
        uint2 kv = *(const uint2*)&kext[nt * 16 + col][0];
        unsigned int a0 = quad == 0 ? kv.x : 0u;
        unsigned int a1 = quad == 0 ? kv.y : 0u;
        bf16x8 f;
        f[0] = (short)(a0 & 0xffffu); f[1] = (short)(a0 >> 16);
        f[2] = (short)(a1 & 0xffffu); f[3] = (short)(a1 >> 16);
        f[4] = 0; f[5] = 0; f[6] = 0; f[7] = 0;
        keext[nt] = f;
    }

    // out-proj accumulators: 2 strips x 32 out-features, f32, live across heads
    f32x4 aggr0[2], aggr1[2];
#pragma unroll
    for (int si = 0; si < 2; si++) {
        aggr0[si] = (f32x4){ 0.f, 0.f, 0.f, 0.f };
        aggr1[si] = (f32x4){ 0.f, 0.f, 0.f, 0.f };
    }

#pragma unroll 1
    for (int h = 0; h < 8; h++) {
        // weight A-fragments for this head (global 16 B loads, L2-resident)
        bf16x8 wfr[6];
#pragma unroll
        for (int g = 0; g < 3; g++)
#pragma unroll
            for (int mt = 0; mt < 2; mt++)
                wfr[g * 2 + mt] = *(const bf16x8*)(wqkvb + (size_t)(g * 256 + h * 32 + mt * 16 + col) * 32 + quad * 8);

        if (h) __syncthreads();                  // prev head's strip readers done

        // ---- staging B: K/V for all 256 tokens, Q for this half's 128 rows ----
#pragma unroll
        for (int si = 0; si < 4; si++) {
            int token = wave * 64 + si * 16 + col;
            int vtk = (token >> 1) & 3;          // swizzle key
            bf16x8 bfx = *(const bf16x8*)&xnb[token][(quad ^ vtk) * 8];
            f32x4 zz = { 0.f, 0.f, 0.f, 0.f };
            if (token >= qbase && token < qbase + 128) {
                int tq = token - qbase;
#pragma unroll
                for (int mt = 0; mt < 2; mt++) {
                    f32x4 z = __builtin_amdgcn_mfma_f32_16x16x32_bf16(wfr[mt], bfx, zz, 0, 0, 0);
                    uint2 u; u.x = pack2bf(z[0], z[1]); u.y = pack2bf(z[2], z[3]);
                    int lc = 2 * mt + (quad >> 1);
                    *(uint2*)&Qb[tq][(lc ^ vtk) * 8 + (quad & 1) * 4] = u;
                }
            }
#pragma unroll
            for (int mt = 0; mt < 2; mt++) {
                f32x4 z = __builtin_amdgcn_mfma_f32_16x16x32_bf16(wfr[2 + mt], bfx, zz, 0, 0, 0);
                uint2 u; u.x = pack2bf(z[0], z[1]); u.y = pack2bf(z[2], z[3]);
                *(uint2*)&Kb[token][mt * 16 + quad * 4] = u;
            }
            int jinv = (token & ~63) + (token & 15) * 4 + ((token >> 4) & 3);
#pragma unroll
            for (int mt = 0; mt < 2; mt++) {
                f32x4 z = __builtin_amdgcn_mfma_f32_16x16x32_bf16(wfr[4 + mt], bfx, zz, 0, 0, 0);
#pragma unroll
                for (int r = 0; r < 4; r++)
                    Vt[mt * 16 + quad * 4 + r][jinv] = f2bf(z[r]);
            }
        }
        __syncthreads();

        // V fragments: invariant across strips -> hoist to registers
        bf16x8 vfr0[8], vfr1[8];
#pragma unroll
        for (int c = 0; c < 4; c++)
#pragma unroll
            for (int k2 = 0; k2 < 2; k2++) {
                vfr0[c * 2 + k2] = *(const bf16x8*)&Vt[col][c * 64 + k2 * 32 + quad * 8];
                vfr1[c * 2 + k2] = *(const bf16x8*)&Vt[16 + col][c * 64 + k2 * 32 + quad * 8];
            }

        float w0 = w2[2 * h], w1 = w2[2 * h + 1];   // already * log2e
        bf16x8 wof0 = *(const bf16x8*)(woutb + (size_t)col * 256 + h * 32 + quad * 8);
        bf16x8 wof1 = *(const bf16x8*)(woutb + (size_t)(16 + col) * 256 + h * 32 + quad * 8);
        unsigned int qp1 = quad == 0 ? pack2bf(-w0, -w1) : 0u;

        // ---- 2 strips of 16 query rows per wave ----
#pragma unroll
        for (int si = 0; si < 2; si++) {
            int trow = wave * 32 + si * 16 + col;      // row within 128-window
            bf16x8 qa = *(const bf16x8*)&Qb[trow][(quad ^ ((trow >> 1) & 3)) * 8];
            float2 pm = pf[qbase + trow];
            unsigned int qp0 = quad == 0 ? pack2bf(2.0f * w0 * pm.x, 2.0f * w1 * pm.y) : 0u;
            bf16x8 qe;
            qe[0] = (short)(qp0 & 0xffffu); qe[1] = (short)(qp0 >> 16);
            qe[2] = (short)(qp1 & 0xffffu); qe[3] = (short)(qp1 >> 16);
            qe[4] = 0; qe[5] = 0; qe[6] = 0; qe[7] = 0;

            f32x4 acc[16];
#pragma unroll
            for (int nt = 0; nt < 16; nt++) {
                bf16x8 kb = *(const bf16x8*)&Kb[nt * 16 + col][quad * 8];
                f32x4 z = { 0.f, 0.f, 0.f, 0.f };
                z = __builtin_amdgcn_mfma_f32_16x16x32_bf16(qa, kb, z, 0, 0, 0);
                acc[nt] = __builtin_amdgcn_mfma_f32_16x16x32_bf16(qe, keext[nt], z, 0, 0, 0);
            }

            // scores in log2 domain -> hardware exp2
            float rsum[4] = { 0.f, 0.f, 0.f, 0.f };
            f32x4 o0 = { 0.f, 0.f, 0.f, 0.f }, o1 = { 0.f, 0.f, 0.f, 0.f };
#pragma unroll
            for (int c = 0; c < 4; c++) {
#pragma unroll
                for (int r = 0; r < 4; r++) {
                    float e0 = __builtin_amdgcn_exp2f(acc[c * 4 + 0][r]);
                    float e1 = __builtin_amdgcn_exp2f(acc[c * 4 + 1][r]);
                    float e2 = __builtin_amdgcn_exp2f(acc[c * 4 + 2][r]);
                    float e3 = __builtin_amdgcn_exp2f(acc[c * 4 + 3][r]);
                    rsum[r] += (e0 + e1) + (e2 + e3);
                    uint2 pk;
                    pk.x = pack2bf(e0, e1);
                    pk.y = pack2bf(e2, e3);
                    *(uint2*)&Pst[wave][quad * 4 + r][col * 4] = pk;  // kloc = col*4+t
                }
#pragma unroll
                for (int k2 = 0; k2 < 2; k2++) {
                    bf16x8 pa = *(const bf16x8*)&Pst[wave][col][k2 * 32 + quad * 8];
                    o0 = __builtin_amdgcn_mfma_f32_16x16x32_bf16(pa, vfr0[c * 2 + k2], o0, 0, 0, 0);
                    o1 = __builtin_amdgcn_mfma_f32_16x16x32_bf16(pa, vfr1[c * 2 + k2], o1, 0, 0, 0);
                }
            }

            // scale by 1/sum, stage O strip, out-proj accumulate
#pragma unroll
            for (int r = 0; r < 4; r++) {
                float su = rsum[r];
                su += __shfl_xor(su, 1); su += __shfl_xor(su, 2);
                su += __shfl_xor(su, 4); su += __shfl_xor(su, 8);
                float rl = __builtin_amdgcn_rcpf(su);
                Pst[wave][quad * 4 + r][col]      = f2bf(o0[r] * rl);
                Pst[wave][quad * 4 + r][col + 16] = f2bf(o1[r] * rl);
            }
            bf16x8 af = *(const bf16x8*)&Pst[wave][col][quad * 8];
            aggr0[si] = __builtin_amdgcn_mfma_f32_16x16x32_bf16(af, wof0, aggr0[si], 0, 0, 0);
            aggr1[si] = __builtin_amdgcn_mfma_f32_16x16x32_bf16(af, wof1, aggr1[si], 0, 0, 0);
        }
    }

    // ---- epilogue: + b_out + residual, LN2, FFN, residual, scatter store ----
    bf16x8 w1f[2], w2f[2];
#pragma unroll
    for (int ct = 0; ct < 2; ct++) {
        w1f[ct] = *(const bf16x8*)(ff1b + (ct * 16 + col) * 32 + quad * 8);
        w2f[ct] = *(const bf16x8*)(ff2b + (ct * 16 + col) * 32 + quad * 8);
    }
    float bo0 = b_out[col], bo1 = b_out[col + 16];
    float g20 = g2[col], g21 = g2[col + 16], be20 = be2[col], be21 = be2[col + 16];
    float fb10 = ffb1[col], fb11 = ffb1[col + 16];
    float fb20 = ffb2[col], fb21 = ffb2[col + 16];

#pragma unroll
    for (int si = 0; si < 2; si++) {
        int rloc = qbase + wave * 32 + si * 16;   // sorted-local row base
        f32x4 a0 = aggr0[si], a1 = aggr1[si];
        int trow[4];
#pragma unroll
        for (int r = 0; r < 4; r++) trow[r] = (int)order[b * 256 + rloc + quad * 4 + r];

#pragma unroll
        for (int r = 0; r < 4; r++) {
            a0[r] += x[(size_t)trow[r] * 32 + col] + bo0;
            a1[r] += x[(size_t)trow[r] * 32 + 16 + col] + bo1;
        }

        f32x4 xn0, xn1;
#pragma unroll
        for (int r = 0; r < 4; r++) {
            float s = a0[r] + a1[r];
            s += __shfl_xor(s, 1); s += __shfl_xor(s, 2); s += __shfl_xor(s, 4); s += __shfl_xor(s, 8);
            float mu = s * (1.0f / 32.0f);
            float c0 = a0[r] - mu, c1 = a1[r] - mu;
            float v = c0 * c0 + c1 * c1;
            v += __shfl_xor(v, 1); v += __shfl_xor(v, 2); v += __shfl_xor(v, 4); v += __shfl_xor(v, 8);
            float rstd = rsqrtf(v * (1.0f / 32.0f) + 1e-5f);
            xn0[r] = c0 * rstd * g20 + be20;
            xn1[r] = c1 * rstd * g21 + be21;
        }

#pragma unroll
        for (int r = 0; r < 4; r++) {
            Pst[wave][quad * 4 + r][col]      = f2bf(xn0[r]);
            Pst[wave][quad * 4 + r][col + 16] = f2bf(xn1[r]);
        }
        bf16x8 af1 = *(const bf16x8*)&Pst[wave][col][quad * 8];
        f32x4 z = { 0.f, 0.f, 0.f, 0.f };
        f32x4 h0 = __builtin_amdgcn_mfma_f32_16x16x32_bf16(af1, w1f[0], z, 0, 0, 0);
        f32x4 h1 = __builtin_amdgcn_mfma_f32_16x16x32_bf16(af1, w1f[1], z, 0, 0, 0);
#pragma unroll
        for (int r = 0; r < 4; r++) {
            h0[r] = fmaxf(h0[r] + fb10, 0.f);
            h1[r] = fmaxf(h1[r] + fb11, 0.f);
        }

#pragma unroll
        for (int r = 0; r < 4; r++) {
            Pst[wave][quad * 4 + r][col]      = f2bf(h0[r]);
            Pst[wave][quad * 4 + r][col + 16] = f2bf(h1[r]);
        }
        bf16x8 af2 = *(const bf16x8*)&Pst[wave][col][quad * 8];
        f32x4 f0 = __builtin_amdgcn_mfma_f32_16x16x32_bf16(af2, w2f[0], z, 0, 0, 0);
        f32x4 f1 = __builtin_amdgcn_mfma_f32_16x16x32_bf16(af2, w2f[1], z, 0, 0, 0);

#pragma unroll
        for (int r = 0; r < 4; r++) {
            out[(size_t)trow[r] * 32 + col]      = a0[r] + f0[r] + fb20;
            out[(size_t)trow[r] * 32 + 16 + col] = a1[r] + f1[r] + fb21;
        }
    }
}

extern "C" void kernel_launch(void* const* d_in, const int* in_sizes, int n_in,
                              void* d_out, int out_size, void* d_ws, size_t ws_size,
                              hipStream_t stream) {
    (void)in_sizes; (void)n_in; (void)out_size; (void)ws_size;
    const float* x      = (const float*)d_in[0];
    const float* coords = (const float*)d_in[1];
    const float* wq     = (const float*)d_in[2];
    const float* wk     = (const float*)d_in[3];
    const float* wv     = (const float*)d_in[4];
    const float* w_rpe  = (const float*)d_in[5];
    const float* w_out  = (const float*)d_in[6];
    const float* b_out  = (const float*)d_in[7];
    const float* g1     = (const float*)d_in[8];
    const float* be1    = (const float*)d_in[9];
    const float* g2     = (const float*)d_in[10];
    const float* be2    = (const float*)d_in[11];
    const float* ffw1   = (const float*)d_in[12];
    const float* ffb1   = (const float*)d_in[13];
    const float* ffw2   = (const float*)d_in[14];
    const float* ffb2   = (const float*)d_in[15];
    float* out = (float*)d_out;

    char* ws = (char*)d_ws;
    unsigned int* hist  = (unsigned int*)(ws);                       // 64K u32
    unsigned int* excl  = (unsigned int*)(ws + 256 * 1024);          // 64K u32
    unsigned int* aux   = (unsigned int*)(ws + 512 * 1024);          // 256 u32
    unsigned int* memb  = (unsigned int*)(ws + 768 * 1024);          // 64K u32
    unsigned int* order = (unsigned int*)(ws + 1024 * 1024);         // 64K u32
    float*        w2    = (float*)(ws + 1280 * 1024);                // 16 f32
    unsigned short* wqkvb = (unsigned short*)(ws + 1536 * 1024);     // 48 KB
    unsigned short* woutb = wqkvb + 24576;
    unsigned short* ff1b  = woutb + 8192;
    unsigned short* ff2b  = ff1b + 1024;

    void* args[] = {
        (void*)&coords, (void*)&wq, (void*)&wk, (void*)&wv, (void*)&w_out,
        (void*)&ffw1, (void*)&ffw2, (void*)&w_rpe,
        (void*)&hist, (void*)&excl, (void*)&aux, (void*)&memb, (void*)&order,
        (void*)&wqkvb, (void*)&woutb, (void*)&ff1b, (void*)&ff2b, (void*)&w2
    };
    hipLaunchCooperativeKernel((const void*)ksortprep, dim3(256), dim3(256),
                               args, 0, stream);
    kattn<<<512, 256, 0, stream>>>(x, g1, be1, wqkvb, order, coords, w2,
                                   woutb, b_out, g2, be2,
                                   ff1b, ffb1, ff2b, ffb2, out);
}

// Round 3
// 246.355 us; speedup vs baseline: 1.4602x; 1.4602x over previous
//
#include <hip/hip_runtime.h>
#include <hip/hip_bf16.h>

#define DEV __device__ __forceinline__

typedef __attribute__((ext_vector_type(8))) short bf16x8;
typedef __attribute__((ext_vector_type(4))) float f32x4;

// N=65536 tokens, 8 heads, head dim 32, feature dim 256, block 256
static constexpr float QSCALE = 0.17677669529663687f; // 1/sqrt(32)
static constexpr float LOG2E  = 1.4426950408889634f;

DEV unsigned short f2bf(float f) {
    union { float f; unsigned int u; } a; a.f = f;
    unsigned int r = (a.u + 0x7fffu + ((a.u >> 16) & 1u)) >> 16; // RNE
    return (unsigned short)r;
}
DEV unsigned int pack2bf(float lo, float hi) {   // v_cvt_pk_bf16_f32 on gfx950
    float2 t; t.x = lo; t.y = hi;
    __hip_bfloat162 h = __float22bfloat162_rn(t);
    unsigned int u; __builtin_memcpy(&u, &h, 4);
    return u;
}

// ---------------- pre-chain, 2 dispatches, no grid sync ----------------
// The final `order` only needs to be the stable argsort of coords[:,0]; with 256
// coarse buckets (top 8 bits, ~256 tokens each, Poisson), ONE block per bucket can
// locally: column-reduce the per-kblock histogram, scan 256 counts, collect its
// members from the compacted key array, and brute-force the stable rank in LDS.
// This replaces memset+hist+scan*3+scatter+rank (8 dispatch boundaries, ~11 us
// each per R1 profile) with 2 dispatches. grid.sync was measured at ~28 us/sync
// (R2: 172 us for <5 us of work) -- cooperative launch abandoned.

// K1: per-block histogram rows + key compaction + weight bf16 prep + w2
__global__ __launch_bounds__(256) void kprep(
    const float* __restrict__ coords,
    const float* __restrict__ wq, const float* __restrict__ wk,
    const float* __restrict__ wv, const float* __restrict__ w_out,
    const float* __restrict__ ff1, const float* __restrict__ ff2,
    const float* __restrict__ w_rpe,
    unsigned int* __restrict__ hist2d,      // [256 kblocks][256 buckets]
    unsigned int* __restrict__ keyarr,      // [65536] float bits of coords[:,0]
    unsigned short* wqkvb, unsigned short* woutb,
    unsigned short* ff1b, unsigned short* ff2b, float* w2)
{
    __shared__ unsigned int hist[256];
    __shared__ float part[4];
    int tid = threadIdx.x;
    int g = blockIdx.x * 256 + tid;

    hist[tid] = 0u;
    float v = coords[(size_t)g * 3];
    keyarr[g] = __float_as_uint(v);          // keys are >= 0 -> bit compare works
    int b8 = (int)(v * 256.0f);
    b8 = b8 < 0 ? 0 : (b8 > 255 ? 255 : b8);
    __syncthreads();
    atomicAdd(&hist[b8], 1u);

    // independent: weight conversion (blocks 0..135) and w2 (blocks 240..255)
    if (g < 34816) {
        int i = g;
        if (i < 8192)        wqkvb[i] = f2bf(wq[i] * (QSCALE * LOG2E));
        else if (i < 16384)  wqkvb[i] = f2bf(wk[i - 8192]);
        else if (i < 24576)  wqkvb[i] = f2bf(wv[i - 16384]);
        else if (i < 32768)  woutb[i - 24576] = f2bf(w_out[i - 24576]);
        else if (i < 33792)  ff1b[i - 32768] = f2bf(ff1[i - 32768]);
        else                 ff2b[i - 33792] = f2bf(ff2[i - 33792]);
    }
    if (blockIdx.x >= 240) {                 // 16 blocks: w2[p], p = h*2 + c
        int p = blockIdx.x - 240;
        int h = p >> 1, c = p & 1;
        int d = tid >> 3, j = tid & 7;
        float w = w_rpe[(h * 32 + d) * 16 + c * 8 + j];
        float w2v = w * w;
        for (int m = 32; m >= 1; m >>= 1) w2v += __shfl_xor(w2v, m);
        if ((tid & 63) == 0) part[tid >> 6] = w2v;
        __syncthreads();
        if (tid == 0) w2[p] = (part[0] + part[1] + part[2] + part[3]) * (1.0f / 256.0f) * LOG2E;
    }
    __syncthreads();
    hist2d[blockIdx.x * 256 + tid] = hist[tid];   // coalesced row write
}

// K2: one block per bucket -> order[]
__global__ __launch_bounds__(256) void kbucket(
    const unsigned int* __restrict__ hist2d,
    const unsigned int* __restrict__ keyarr,
    unsigned int* __restrict__ order)
{
    __shared__ unsigned int s[256];
    __shared__ unsigned int mkey[1024];
    __shared__ unsigned int midx[1024];
    __shared__ unsigned int mcount;
    int tid = threadIdx.x;
    int b = blockIdx.x;

    // column-reduce hist2d: counts[tid] = sum_k hist2d[k][tid]  (coalesced rows)
    unsigned int cnt = 0;
    for (int k = 0; k < 256; k++) cnt += hist2d[k * 256 + tid];

    // exclusive scan over 256 bucket counts (Hillis-Steele in LDS)
    s[tid] = cnt; __syncthreads();
    for (int off = 1; off < 256; off <<= 1) {
        unsigned int t = (tid >= off) ? s[tid - off] : 0u;
        __syncthreads();
        s[tid] += t;
        __syncthreads();
    }
    unsigned int start = (b == 0) ? 0u : s[b - 1];   // this bucket's global offset

    if (tid == 0) mcount = 0u;
    __syncthreads();

    // collect this bucket's members from the compacted key array (coalesced)
    for (int it = 0; it < 256; it++) {
        int i = it * 256 + tid;
        unsigned int kb = keyarr[i];
        float v = __uint_as_float(kb);
        int b8 = (int)(v * 256.0f);
        b8 = b8 < 0 ? 0 : (b8 > 255 ? 255 : b8);
        if (b8 == b) {
            unsigned int p = atomicAdd(&mcount, 1u);
            if (p < 1024u) { mkey[p] = kb; midx[p] = (unsigned int)i; }
        }
    }
    __syncthreads();
    unsigned int cntb = mcount < 1024u ? mcount : 1024u;

    // stable rank via lockstep-broadcast O(cnt^2) compare (cnt ~ 256 +- 50)
    for (unsigned int m = tid; m < cntb; m += 256) {
        unsigned int km = mkey[m], im = midx[m];
        unsigned int r = 0;
        for (unsigned int j = 0; j < cntb; j++) {
            unsigned int kj = mkey[j];
            r += (kj < km || (kj == km && midx[j] < im)) ? 1u : 0u;
        }
        order[start + r] = im;
    }
}

// ---------------- fully fused: LN1 + QKV + attention(8 heads) + out-proj +
// residual + LN2 + FFN + residual, per (bucket, query-half) block ----------------
// Grid 512 = 256 buckets x 2 query-halves, 256 threads (4 waves), 2 blocks/CU.
// Out-proj decomposes per head: aggr += O_h @ w_out_h^T accumulated in f32 MFMA
// accumulators across a rolled 8-head loop. K/V generated for all 256 tokens per
// block (x2 duplication across halves); Q only for the 128 owned rows.
// Bias head-independent on the K side: keext = [a, b, a^2, b^2], query side
// carries [2w0 a_i, 2w1 b_i, -w0, -w1].
// Block swizzle: both halves of a bucket share blockIdx%8 -> same XCD L2.
// LDS: xnb 16384 + Qb 8192 + Kb 20480 + Vt 16896 + kext 2048 + pf 2048
//      + Pst 9216 = 75264 B -> 2 blocks/CU.
__global__ __launch_bounds__(256, 2) void kattn(
    const float* __restrict__ x, const float* __restrict__ g1, const float* __restrict__ be1,
    const unsigned short* __restrict__ wqkvb,
    const unsigned int* __restrict__ order, const float* __restrict__ coords,
    const float* __restrict__ w2,
    const unsigned short* __restrict__ woutb, const float* __restrict__ b_out,
    const float* __restrict__ g2, const float* __restrict__ be2,
    const unsigned short* __restrict__ ff1b, const float* __restrict__ ffb1,
    const unsigned short* __restrict__ ff2b, const float* __restrict__ ffb2,
    float* __restrict__ out)
{
    __shared__ unsigned short xnb[256][32];     // 16384 B  LN'd x, swizzled chunks
    __shared__ unsigned short Qb[128][32];      //  8192 B  this half's Q, swizzled
    __shared__ unsigned short Kb[256][40];      // 20480 B  padded (conflict-free)
    __shared__ unsigned short Vt[32][264];      // 16896 B  [feature][permuted token]
    __shared__ unsigned short kext[256][4];     //  2048 B  {a, b, a^2, b^2} bf16
    __shared__ float2 pf[256];                  //  2048 B  f32 coords for Q side
    __shared__ unsigned short Pst[4][16][72];   //  9216 B  per-wave strip staging

    int bh = blockIdx.x;
    int b = (bh & 7) * 32 + ((bh >> 3) & 31);   // bucket; both halves share bh%8 (XCD)
    int qbase = (bh >> 8) * 128;                // query-row window base (0 or 128)
    int tid = threadIdx.x, wave = tid >> 6, lane = tid & 63;
    int col = lane & 15, quad = lane >> 4;

    // ---- stage A: gather x row, LN1 -> xnb (swizzled); coords -> kext/pf ----
    {
        int t = tid;
        int tok = (int)order[b * 256 + t];
        float a = coords[tok * 3 + 1], bb = coords[tok * 3 + 2];
        pf[t] = make_float2(a, bb);
        uint2 kv;
        kv.x = pack2bf(a, bb);
        kv.y = pack2bf(a * a, bb * bb);
        *(uint2*)&kext[t][0] = kv;

        float xv[32];
        const float4* xr = (const float4*)(x + (size_t)tok * 32);
#pragma unroll
        for (int q4 = 0; q4 < 8; q4++) {
            float4 v4 = xr[q4];
            xv[q4 * 4 + 0] = v4.x; xv[q4 * 4 + 1] = v4.y; xv[q4 * 4 + 2] = v4.z; xv[q4 * 4 + 3] = v4.w;
        }
        float mu = 0.f;
#pragma unroll
        for (int d = 0; d < 32; d++) mu += xv[d];
        mu *= (1.0f / 32.0f);
        float var = 0.f;
#pragma unroll
        for (int d = 0; d < 32; d++) { float c = xv[d] - mu; var += c * c; }
        var *= (1.0f / 32.0f);
        float rstd = rsqrtf(var + 1e-5f);
        unsigned int pk[16];
#pragma unroll
        for (int w = 0; w < 16; w++) {
            float a2 = (xv[2 * w] - mu) * rstd * g1[2 * w] + be1[2 * w];
            float b2 = (xv[2 * w + 1] - mu) * rstd * g1[2 * w + 1] + be1[2 * w + 1];
            pk[w] = pack2bf(a2, b2);
        }
        int v = (t >> 1) & 3;                    // chunk swizzle key
        uint4* dst = (uint4*)&xnb[t][0];
#pragma unroll
        for (int w4 = 0; w4 < 4; w4++) {
            uint4 v4; v4.x = pk[w4*4]; v4.y = pk[w4*4+1]; v4.z = pk[w4*4+2]; v4.w = pk[w4*4+3];
            dst[w4 ^ v] = v4;                    // logical chunk w4 -> physical w4^v
        }
    }
    __syncthreads();

    // extended-K fragments: head-independent {a, b, a^2, b^2} -> hoist once
    bf16x8 keext[16];
#pragma unroll
    for (int nt = 0; nt < 16; nt++) {
        uint2 kv = *(const uint2*)&kext[nt * 16 + col][0];
        unsigned int a0 = quad == 0 ? kv.x : 0u;
        unsigned int a1 = quad == 0 ? kv.y : 0u;
        bf16x8 f;
        f[0] = (short)(a0 & 0xffffu); f[1] = (short)(a0 >> 16);
        f[2] = (short)(a1 & 0xffffu); f[3] = (short)(a1 >> 16);
        f[4] = 0; f[5] = 0; f[6] = 0; f[7] = 0;
        keext[nt] = f;
    }

    // out-proj accumulators: 2 strips x 32 out-features, f32, live across heads
    f32x4 aggr0[2], aggr1[2];
#pragma unroll
    for (int si = 0; si < 2; si++) {
        aggr0[si] = (f32x4){ 0.f, 0.f, 0.f, 0.f };
        aggr1[si] = (f32x4){ 0.f, 0.f, 0.f, 0.f };
    }

#pragma unroll 1
    for (int h = 0; h < 8; h++) {
        // weight A-fragments for this head (global 16 B loads, L2-resident)
        bf16x8 wfr[6];
#pragma unroll
        for (int g = 0; g < 3; g++)
#pragma unroll
            for (int mt = 0; mt < 2; mt++)
                wfr[g * 2 + mt] = *(const bf16x8*)(wqkvb + (size_t)(g * 256 + h * 32 + mt * 16 + col) * 32 + quad * 8);

        if (h) __syncthreads();                  // prev head's strip readers done

        // ---- staging B: K/V for all 256 tokens, Q for this half's 128 rows ----
#pragma unroll
        for (int si = 0; si < 4; si++) {
            int token = wave * 64 + si * 16 + col;
            int vtk = (token >> 1) & 3;          // swizzle key
            bf16x8 bfx = *(const bf16x8*)&xnb[token][(quad ^ vtk) * 8];
            f32x4 zz = { 0.f, 0.f, 0.f, 0.f };
            if (token >= qbase && token < qbase + 128) {
                int tq = token - qbase;
#pragma unroll
                for (int mt = 0; mt < 2; mt++) {
                    f32x4 z = __builtin_amdgcn_mfma_f32_16x16x32_bf16(wfr[mt], bfx, zz, 0, 0, 0);
                    uint2 u; u.x = pack2bf(z[0], z[1]); u.y = pack2bf(z[2], z[3]);
                    int lc = 2 * mt + (quad >> 1);
                    *(uint2*)&Qb[tq][(lc ^ vtk) * 8 + (quad & 1) * 4] = u;
                }
            }
#pragma unroll
            for (int mt = 0; mt < 2; mt++) {
                f32x4 z = __builtin_amdgcn_mfma_f32_16x16x32_bf16(wfr[2 + mt], bfx, zz, 0, 0, 0);
                uint2 u; u.x = pack2bf(z[0], z[1]); u.y = pack2bf(z[2], z[3]);
                *(uint2*)&Kb[token][mt * 16 + quad * 4] = u;
            }
            int jinv = (token & ~63) + (token & 15) * 4 + ((token >> 4) & 3);
#pragma unroll
            for (int mt = 0; mt < 2; mt++) {
                f32x4 z = __builtin_amdgcn_mfma_f32_16x16x32_bf16(wfr[4 + mt], bfx, zz, 0, 0, 0);
#pragma unroll
                for (int r = 0; r < 4; r++)
                    Vt[mt * 16 + quad * 4 + r][jinv] = f2bf(z[r]);
            }
        }
        __syncthreads();

        // V fragments: invariant across strips -> hoist to registers
        bf16x8 vfr0[8], vfr1[8];
#pragma unroll
        for (int c = 0; c < 4; c++)
#pragma unroll
            for (int k2 = 0; k2 < 2; k2++) {
                vfr0[c * 2 + k2] = *(const bf16x8*)&Vt[col][c * 64 + k2 * 32 + quad * 8];
                vfr1[c * 2 + k2] = *(const bf16x8*)&Vt[16 + col][c * 64 + k2 * 32 + quad * 8];
            }

        float w0 = w2[2 * h], w1 = w2[2 * h + 1];   // already * log2e
        bf16x8 wof0 = *(const bf16x8*)(woutb + (size_t)col * 256 + h * 32 + quad * 8);
        bf16x8 wof1 = *(const bf16x8*)(woutb + (size_t)(16 + col) * 256 + h * 32 + quad * 8);
        unsigned int qp1 = quad == 0 ? pack2bf(-w0, -w1) : 0u;

        // ---- 2 strips of 16 query rows per wave ----
#pragma unroll
        for (int si = 0; si < 2; si++) {
            int trow = wave * 32 + si * 16 + col;      // row within 128-window
            bf16x8 qa = *(const bf16x8*)&Qb[trow][(quad ^ ((trow >> 1) & 3)) * 8];
            float2 pm = pf[qbase + trow];
            unsigned int qp0 = quad == 0 ? pack2bf(2.0f * w0 * pm.x, 2.0f * w1 * pm.y) : 0u;
            bf16x8 qe;
            qe[0] = (short)(qp0 & 0xffffu); qe[1] = (short)(qp0 >> 16);
            qe[2] = (short)(qp1 & 0xffffu); qe[3] = (short)(qp1 >> 16);
            qe[4] = 0; qe[5] = 0; qe[6] = 0; qe[7] = 0;

            f32x4 acc[16];
#pragma unroll
            for (int nt = 0; nt < 16; nt++) {
                bf16x8 kb = *(const bf16x8*)&Kb[nt * 16 + col][quad * 8];
                f32x4 z = { 0.f, 0.f, 0.f, 0.f };
                z = __builtin_amdgcn_mfma_f32_16x16x32_bf16(qa, kb, z, 0, 0, 0);
                acc[nt] = __builtin_amdgcn_mfma_f32_16x16x32_bf16(qe, keext[nt], z, 0, 0, 0);
            }

            // scores in log2 domain -> hardware exp2
            float rsum[4] = { 0.f, 0.f, 0.f, 0.f };
            f32x4 o0 = { 0.f, 0.f, 0.f, 0.f }, o1 = { 0.f, 0.f, 0.f, 0.f };
#pragma unroll
            for (int c = 0; c < 4; c++) {
#pragma unroll
                for (int r = 0; r < 4; r++) {
                    float e0 = __builtin_amdgcn_exp2f(acc[c * 4 + 0][r]);
                    float e1 = __builtin_amdgcn_exp2f(acc[c * 4 + 1][r]);
                    float e2 = __builtin_amdgcn_exp2f(acc[c * 4 + 2][r]);
                    float e3 = __builtin_amdgcn_exp2f(acc[c * 4 + 3][r]);
                    rsum[r] += (e0 + e1) + (e2 + e3);
                    uint2 pk;
                    pk.x = pack2bf(e0, e1);
                    pk.y = pack2bf(e2, e3);
                    *(uint2*)&Pst[wave][quad * 4 + r][col * 4] = pk;  // kloc = col*4+t
                }
#pragma unroll
                for (int k2 = 0; k2 < 2; k2++) {
                    bf16x8 pa = *(const bf16x8*)&Pst[wave][col][k2 * 32 + quad * 8];
                    o0 = __builtin_amdgcn_mfma_f32_16x16x32_bf16(pa, vfr0[c * 2 + k2], o0, 0, 0, 0);
                    o1 = __builtin_amdgcn_mfma_f32_16x16x32_bf16(pa, vfr1[c * 2 + k2], o1, 0, 0, 0);
                }
            }

            // scale by 1/sum, stage O strip, out-proj accumulate
#pragma unroll
            for (int r = 0; r < 4; r++) {
                float su = rsum[r];
                su += __shfl_xor(su, 1); su += __shfl_xor(su, 2);
                su += __shfl_xor(su, 4); su += __shfl_xor(su, 8);
                float rl = __builtin_amdgcn_rcpf(su);
                Pst[wave][quad * 4 + r][col]      = f2bf(o0[r] * rl);
                Pst[wave][quad * 4 + r][col + 16] = f2bf(o1[r] * rl);
            }
            bf16x8 af = *(const bf16x8*)&Pst[wave][col][quad * 8];
            aggr0[si] = __builtin_amdgcn_mfma_f32_16x16x32_bf16(af, wof0, aggr0[si], 0, 0, 0);
            aggr1[si] = __builtin_amdgcn_mfma_f32_16x16x32_bf16(af, wof1, aggr1[si], 0, 0, 0);
        }
    }

    // ---- epilogue: + b_out + residual, LN2, FFN, residual, scatter store ----
    bf16x8 w1f[2], w2f[2];
#pragma unroll
    for (int ct = 0; ct < 2; ct++) {
        w1f[ct] = *(const bf16x8*)(ff1b + (ct * 16 + col) * 32 + quad * 8);
        w2f[ct] = *(const bf16x8*)(ff2b + (ct * 16 + col) * 32 + quad * 8);
    }
    float bo0 = b_out[col], bo1 = b_out[col + 16];
    float g20 = g2[col], g21 = g2[col + 16], be20 = be2[col], be21 = be2[col + 16];
    float fb10 = ffb1[col], fb11 = ffb1[col + 16];
    float fb20 = ffb2[col], fb21 = ffb2[col + 16];

#pragma unroll
    for (int si = 0; si < 2; si++) {
        int rloc = qbase + wave * 32 + si * 16;   // sorted-local row base
        f32x4 a0 = aggr0[si], a1 = aggr1[si];
        int trow[4];
#pragma unroll
        for (int r = 0; r < 4; r++) trow[r] = (int)order[b * 256 + rloc + quad * 4 + r];

#pragma unroll
        for (int r = 0; r < 4; r++) {
            a0[r] += x[(size_t)trow[r] * 32 + col] + bo0;
            a1[r] += x[(size_t)trow[r] * 32 + 16 + col] + bo1;
        }

        f32x4 xn0, xn1;
#pragma unroll
        for (int r = 0; r < 4; r++) {
            float s = a0[r] + a1[r];
            s += __shfl_xor(s, 1); s += __shfl_xor(s, 2); s += __shfl_xor(s, 4); s += __shfl_xor(s, 8);
            float mu = s * (1.0f / 32.0f);
            float c0 = a0[r] - mu, c1 = a1[r] - mu;
            float v = c0 * c0 + c1 * c1;
            v += __shfl_xor(v, 1); v += __shfl_xor(v, 2); v += __shfl_xor(v, 4); v += __shfl_xor(v, 8);
            float rstd = rsqrtf(v * (1.0f / 32.0f) + 1e-5f);
            xn0[r] = c0 * rstd * g20 + be20;
            xn1[r] = c1 * rstd * g21 + be21;
        }

#pragma unroll
        for (int r = 0; r < 4; r++) {
            Pst[wave][quad * 4 + r][col]      = f2bf(xn0[r]);
            Pst[wave][quad * 4 + r][col + 16] = f2bf(xn1[r]);
        }
        bf16x8 af1 = *(const bf16x8*)&Pst[wave][col][quad * 8];
        f32x4 z = { 0.f, 0.f, 0.f, 0.f };
        f32x4 h0 = __builtin_amdgcn_mfma_f32_16x16x32_bf16(af1, w1f[0], z, 0, 0, 0);
        f32x4 h1 = __builtin_amdgcn_mfma_f32_16x16x32_bf16(af1, w1f[1], z, 0, 0, 0);
#pragma unroll
        for (int r = 0; r < 4; r++) {
            h0[r] = fmaxf(h0[r] + fb10, 0.f);
            h1[r] = fmaxf(h1[r] + fb11, 0.f);
        }

#pragma unroll
        for (int r = 0; r < 4; r++) {
            Pst[wave][quad * 4 + r][col]      = f2bf(h0[r]);
            Pst[wave][quad * 4 + r][col + 16] = f2bf(h1[r]);
        }
        bf16x8 af2 = *(const bf16x8*)&Pst[wave][col][quad * 8];
        f32x4 f0 = __builtin_amdgcn_mfma_f32_16x16x32_bf16(af2, w2f[0], z, 0, 0, 0);
        f32x4 f1 = __builtin_amdgcn_mfma_f32_16x16x32_bf16(af2, w2f[1], z, 0, 0, 0);

#pragma unroll
        for (int r = 0; r < 4; r++) {
            out[(size_t)trow[r] * 32 + col]      = a0[r] + f0[r] + fb20;
            out[(size_t)trow[r] * 32 + 16 + col] = a1[r] + f1[r] + fb21;
        }
    }
}

extern "C" void kernel_launch(void* const* d_in, const int* in_sizes, int n_in,
                              void* d_out, int out_size, void* d_ws, size_t ws_size,
                              hipStream_t stream) {
    (void)in_sizes; (void)n_in; (void)out_size; (void)ws_size;
    const float* x      = (const float*)d_in[0];
    const float* coords = (const float*)d_in[1];
    const float* wq     = (const float*)d_in[2];
    const float* wk     = (const float*)d_in[3];
    const float* wv     = (const float*)d_in[4];
    const float* w_rpe  = (const float*)d_in[5];
    const float* w_out  = (const float*)d_in[6];
    const float* b_out  = (const float*)d_in[7];
    const float* g1     = (const float*)d_in[8];
    const float* be1    = (const float*)d_in[9];
    const float* g2     = (const float*)d_in[10];
    const float* be2    = (const float*)d_in[11];
    const float* ffw1   = (const float*)d_in[12];
    const float* ffb1   = (const float*)d_in[13];
    const float* ffw2   = (const float*)d_in[14];
    const float* ffb2   = (const float*)d_in[15];
    float* out = (float*)d_out;

    char* ws = (char*)d_ws;
    unsigned int* hist2d = (unsigned int*)(ws);                      // 256 KB
    unsigned int* keyarr = (unsigned int*)(ws + 256 * 1024);         // 256 KB
    unsigned int* order  = (unsigned int*)(ws + 1024 * 1024);        // 256 KB
    float*        w2     = (float*)(ws + 1280 * 1024);               // 16 f32
    unsigned short* wqkvb = (unsigned short*)(ws + 1536 * 1024);     // 48 KB
    unsigned short* woutb = wqkvb + 24576;
    unsigned short* ff1b  = woutb + 8192;
    unsigned short* ff2b  = ff1b + 1024;

    kprep  <<<256, 256, 0, stream>>>(coords, wq, wk, wv, w_out, ffw1, ffw2, w_rpe,
                                     hist2d, keyarr, wqkvb, woutb, ff1b, ff2b, w2);
    kbucket<<<256, 256, 0, stream>>>(hist2d, keyarr, order);
    kattn  <<<512, 256, 0, stream>>>(x, g1, be1, wqkvb, order, coords, w2,
                                     woutb, b_out, g2, be2,
                                     ff1b, ffb1, ff2b, ffb2, out);
}

// Round 4
// 190.220 us; speedup vs baseline: 1.8911x; 1.2951x over previous
//
#include <hip/hip_runtime.h>
#include <hip/hip_bf16.h>

#define DEV __device__ __forceinline__

typedef __attribute__((ext_vector_type(8))) short bf16x8;
typedef __attribute__((ext_vector_type(4))) float f32x4;

// N=65536 tokens, 8 heads, head dim 32, feature dim 256, block 256
static constexpr float QSCALE = 0.17677669529663687f; // 1/sqrt(32)
static constexpr float LOG2E  = 1.4426950408889634f;

DEV unsigned short f2bf(float f) {
    union { float f; unsigned int u; } a; a.f = f;
    unsigned int r = (a.u + 0x7fffu + ((a.u >> 16) & 1u)) >> 16; // RNE
    return (unsigned short)r;
}
DEV unsigned int pack2bf(float lo, float hi) {   // v_cvt_pk_bf16_f32 on gfx950
    float2 t; t.x = lo; t.y = hi;
    __hip_bfloat162 h = __float22bfloat162_rn(t);
    unsigned int u; __builtin_memcpy(&u, &h, 4);
    return u;
}

// ---------------- pre-chain, 2 dispatches, no serial O(N) loops ----------------
// R3 lesson: kbucket's per-block O(N) latency-chained scans cost 91 us (VALUBusy
// 6%, HBM 0.3% -- pure load-latency serialization). Fix: kprep performs a
// block-local counting sort (LDS atomics + LDS scan) writing bucket-grouped
// locmemb + per-(kblock,bucket) counts/offsets; kbucket then touches only its
// own ~256 members: unrolled column-sum + 2 strided gathers + LDS scans +
// O(cnt^2) lockstep rank. Arrival order within a (k,b) cell is arbitrary --
// final rank compares (key, idx) exactly, so grouping needs no stability.

// K1: block-local counting sort + keyarr + weight bf16 prep + w2
__global__ __launch_bounds__(256) void kprep(
    const float* __restrict__ coords,
    const float* __restrict__ wq, const float* __restrict__ wk,
    const float* __restrict__ wv, const float* __restrict__ w_out,
    const float* __restrict__ ff1, const float* __restrict__ ff2,
    const float* __restrict__ w_rpe,
    unsigned int* __restrict__ hist2d,      // [256 kblocks][256 buckets] counts
    unsigned int* __restrict__ lstart,      // [256 kblocks][256 buckets] local excl off
    unsigned int* __restrict__ locmemb,     // [256 kblocks][256] bucket-grouped ids
    unsigned int* __restrict__ keyarr,      // [65536] float bits of coords[:,0]
    unsigned short* wqkvb, unsigned short* woutb,
    unsigned short* ff1b, unsigned short* ff2b, float* w2)
{
    __shared__ unsigned int lhist[256];
    __shared__ unsigned int s[256];
    __shared__ unsigned int loff[256];
    __shared__ float part[4];
    int tid = threadIdx.x;
    int g = blockIdx.x * 256 + tid;

    lhist[tid] = 0u;
    float v = coords[(size_t)g * 3];
    keyarr[g] = __float_as_uint(v);          // keys >= 0 -> bit compare works
    int b8 = (int)(v * 256.0f);
    b8 = b8 < 0 ? 0 : (b8 > 255 ? 255 : b8);
    __syncthreads();
    unsigned int myl = atomicAdd(&lhist[b8], 1u);

    // independent work: weight conversion and w2 (block-uniform branches)
    if (g < 34816) {
        int i = g;
        if (i < 8192)        wqkvb[i] = f2bf(wq[i] * (QSCALE * LOG2E));
        else if (i < 16384)  wqkvb[i] = f2bf(wk[i - 8192]);
        else if (i < 24576)  wqkvb[i] = f2bf(wv[i - 16384]);
        else if (i < 32768)  woutb[i - 24576] = f2bf(w_out[i - 24576]);
        else if (i < 33792)  ff1b[i - 32768] = f2bf(ff1[i - 32768]);
        else                 ff2b[i - 33792] = f2bf(ff2[i - 33792]);
    }
    if (blockIdx.x >= 240) {                 // 16 blocks: w2[p], p = h*2 + c
        int p = blockIdx.x - 240;
        int h = p >> 1, c = p & 1;
        int d = tid >> 3, j = tid & 7;
        float w = w_rpe[(h * 32 + d) * 16 + c * 8 + j];
        float w2v = w * w;
        for (int m = 32; m >= 1; m >>= 1) w2v += __shfl_xor(w2v, m);
        if ((tid & 63) == 0) part[tid >> 6] = w2v;
        __syncthreads();
        if (tid == 0) w2[p] = (part[0] + part[1] + part[2] + part[3]) * (1.0f / 256.0f) * LOG2E;
    }
    __syncthreads();

    // block-local exclusive scan of bucket counts
    unsigned int cnt = lhist[tid];
    s[tid] = cnt; __syncthreads();
    for (int off = 1; off < 256; off <<= 1) {
        unsigned int t = (tid >= off) ? s[tid - off] : 0u;
        __syncthreads();
        s[tid] += t;
        __syncthreads();
    }
    unsigned int lexcl = s[tid] - cnt;
    loff[tid] = lexcl;
    hist2d[blockIdx.x * 256 + tid] = cnt;     // coalesced
    lstart[blockIdx.x * 256 + tid] = lexcl;   // coalesced
    __syncthreads();

    // block-local bucket-grouped scatter (all targets within this block's row)
    locmemb[blockIdx.x * 256 + loff[b8] + myl] = (unsigned int)g;
}

// K2: one block per bucket -> exact stable order[] (O(cnt) loads + O(cnt^2) LDS rank)
__global__ __launch_bounds__(256) void kbucket(
    const unsigned int* __restrict__ hist2d,
    const unsigned int* __restrict__ lstart,
    const unsigned int* __restrict__ locmemb,
    const unsigned int* __restrict__ keyarr,
    unsigned int* __restrict__ order)
{
    __shared__ unsigned int s[256];
    __shared__ unsigned int mkey[512];
    __shared__ unsigned int midx[512];
    int tid = threadIdx.x;
    int b = blockIdx.x;

    // total count per bucket: column-sum of hist2d (coalesced rows, unrolled -> pipelined)
    unsigned int total = 0;
#pragma unroll 16
    for (int k = 0; k < 256; k++) total += hist2d[k * 256 + tid];

    // inclusive scan over bucket totals -> global start of bucket b
    s[tid] = total; __syncthreads();
    for (int off = 1; off < 256; off <<= 1) {
        unsigned int t = (tid >= off) ? s[tid - off] : 0u;
        __syncthreads();
        s[tid] += t;
        __syncthreads();
    }
    unsigned int start = (b == 0) ? 0u : s[b - 1];
    __syncthreads();

    // this bucket's segment in each kblock (two strided gathers, 1 round each)
    unsigned int segcnt = hist2d[tid * 256 + b];
    unsigned int segoff = lstart[tid * 256 + b];

    // exclusive scan of segment counts -> LDS destinations
    s[tid] = segcnt; __syncthreads();
    for (int off = 1; off < 256; off <<= 1) {
        unsigned int t = (tid >= off) ? s[tid - off] : 0u;
        __syncthreads();
        s[tid] += t;
        __syncthreads();
    }
    unsigned int dst = s[tid] - segcnt;
    unsigned int cntb = s[255];
    if (cntb > 512u) cntb = 512u;             // statistically impossible; OOB guard
    __syncthreads();

    // copy member ids (avg 1 per thread), then batch-gather keys in one round
    for (unsigned int j = 0; j < segcnt; j++) {
        unsigned int p = dst + j;
        if (p < 512u) midx[p] = locmemb[tid * 256 + segoff + j];
    }
    __syncthreads();
    for (unsigned int p = tid; p < cntb; p += 256) mkey[p] = keyarr[midx[p]];
    __syncthreads();

    // stable rank via lockstep-broadcast O(cnt^2) compare (cnt ~ 256 +- 50)
    for (unsigned int m = tid; m < cntb; m += 256) {
        unsigned int km = mkey[m], im = midx[m];
        unsigned int r = 0;
        for (unsigned int j = 0; j < cntb; j++) {
            unsigned int kj = mkey[j];
            r += (kj < km || (kj == km && midx[j] < im)) ? 1u : 0u;
        }
        order[start + r] = im;
    }
}

// ---------------- fully fused: LN1 + QKV + attention(8 heads) + out-proj +
// residual + LN2 + FFN + residual, per (bucket, query-half) block ----------------
// Grid 512 = 256 buckets x 2 query-halves, 256 threads (4 waves), 2 blocks/CU.
// Out-proj decomposes per head: aggr += O_h @ w_out_h^T accumulated in f32 MFMA
// accumulators across a rolled 8-head loop. K/V generated for all 256 tokens per
// block (x2 duplication across halves); Q only for the 128 owned rows.
// Bias head-independent on the K side: keext = [a, b, a^2, b^2], query side
// carries [2w0 a_i, 2w1 b_i, -w0, -w1].
// Block swizzle: both halves of a bucket share blockIdx%8 -> same XCD L2.
// LDS: xnb 16384 + Qb 8192 + Kb 20480 + Vt 16896 + kext 2048 + pf 2048
//      + Pst 9216 = 75264 B -> 2 blocks/CU.
__global__ __launch_bounds__(256, 2) void kattn(
    const float* __restrict__ x, const float* __restrict__ g1, const float* __restrict__ be1,
    const unsigned short* __restrict__ wqkvb,
    const unsigned int* __restrict__ order, const float* __restrict__ coords,
    const float* __restrict__ w2,
    const unsigned short* __restrict__ woutb, const float* __restrict__ b_out,
    const float* __restrict__ g2, const float* __restrict__ be2,
    const unsigned short* __restrict__ ff1b, const float* __restrict__ ffb1,
    const unsigned short* __restrict__ ff2b, const float* __restrict__ ffb2,
    float* __restrict__ out)
{
    __shared__ unsigned short xnb[256][32];     // 16384 B  LN'd x, swizzled chunks
    __shared__ unsigned short Qb[128][32];      //  8192 B  this half's Q, swizzled
    __shared__ unsigned short Kb[256][40];      // 20480 B  padded (conflict-free)
    __shared__ unsigned short Vt[32][264];      // 16896 B  [feature][permuted token]
    __shared__ unsigned short kext[256][4];     //  2048 B  {a, b, a^2, b^2} bf16
    __shared__ float2 pf[256];                  //  2048 B  f32 coords for Q side
    __shared__ unsigned short Pst[4][16][72];   //  9216 B  per-wave strip staging

    int bh = blockIdx.x;
    int b = (bh & 7) * 32 + ((bh >> 3) & 31);   // bucket; both halves share bh%8 (XCD)
    int qbase = (bh >> 8) * 128;                // query-row window base (0 or 128)
    int tid = threadIdx.x, wave = tid >> 6, lane = tid & 63;
    int col = lane & 15, quad = lane >> 4;

    // ---- stage A: gather x row, LN1 -> xnb (swizzled); coords -> kext/pf ----
    {
        int t = tid;
        int tok = (int)order[b * 256 + t];
        float a = coords[tok * 3 + 1], bb = coords[tok * 3 + 2];
        pf[t] = make_float2(a, bb);
        uint2 kv;
        kv.x = pack2bf(a, bb);
        kv.y = pack2bf(a * a, bb * bb);
        *(uint2*)&kext[t][0] = kv;

        float xv[32];
        const float4* xr = (const float4*)(x + (size_t)tok * 32);
#pragma unroll
        for (int q4 = 0; q4 < 8; q4++) {
            float4 v4 = xr[q4];
            xv[q4 * 4 + 0] = v4.x; xv[q4 * 4 + 1] = v4.y; xv[q4 * 4 + 2] = v4.z; xv[q4 * 4 + 3] = v4.w;
        }
        float mu = 0.f;
#pragma unroll
        for (int d = 0; d < 32; d++) mu += xv[d];
        mu *= (1.0f / 32.0f);
        float var = 0.f;
#pragma unroll
        for (int d = 0; d < 32; d++) { float c = xv[d] - mu; var += c * c; }
        var *= (1.0f / 32.0f);
        float rstd = rsqrtf(var + 1e-5f);
        unsigned int pk[16];
#pragma unroll
        for (int w = 0; w < 16; w++) {
            float a2 = (xv[2 * w] - mu) * rstd * g1[2 * w] + be1[2 * w];
            float b2 = (xv[2 * w + 1] - mu) * rstd * g1[2 * w + 1] + be1[2 * w + 1];
            pk[w] = pack2bf(a2, b2);
        }
        int v = (t >> 1) & 3;                    // chunk swizzle key
        uint4* dst = (uint4*)&xnb[t][0];
#pragma unroll
        for (int w4 = 0; w4 < 4; w4++) {
            uint4 v4; v4.x = pk[w4*4]; v4.y = pk[w4*4+1]; v4.z = pk[w4*4+2]; v4.w = pk[w4*4+3];
            dst[w4 ^ v] = v4;                    // logical chunk w4 -> physical w4^v
        }
    }
    __syncthreads();

    // extended-K fragments: head-independent {a, b, a^2, b^2} -> hoist once
    bf16x8 keext[16];
#pragma unroll
    for (int nt = 0; nt < 16; nt++) {
        uint2 kv = *(const uint2*)&kext[nt * 16 + col][0];
        unsigned int a0 = quad == 0 ? kv.x : 0u;
        unsigned int a1 = quad == 0 ? kv.y : 0u;
        bf16x8 f;
        f[0] = (short)(a0 & 0xffffu); f[1] = (short)(a0 >> 16);
        f[2] = (short)(a1 & 0xffffu); f[3] = (short)(a1 >> 16);
        f[4] = 0; f[5] = 0; f[6] = 0; f[7] = 0;
        keext[nt] = f;
    }

    // out-proj accumulators: 2 strips x 32 out-features, f32, live across heads
    f32x4 aggr0[2], aggr1[2];
#pragma unroll
    for (int si = 0; si < 2; si++) {
        aggr0[si] = (f32x4){ 0.f, 0.f, 0.f, 0.f };
        aggr1[si] = (f32x4){ 0.f, 0.f, 0.f, 0.f };
    }

#pragma unroll 1
    for (int h = 0; h < 8; h++) {
        // weight A-fragments for this head (global 16 B loads, L2-resident)
        bf16x8 wfr[6];
#pragma unroll
        for (int g = 0; g < 3; g++)
#pragma unroll
            for (int mt = 0; mt < 2; mt++)
                wfr[g * 2 + mt] = *(const bf16x8*)(wqkvb + (size_t)(g * 256 + h * 32 + mt * 16 + col) * 32 + quad * 8);

        if (h) __syncthreads();                  // prev head's strip readers done

        // ---- staging B: K/V for all 256 tokens, Q for this half's 128 rows ----
#pragma unroll
        for (int si = 0; si < 4; si++) {
            int token = wave * 64 + si * 16 + col;
            int vtk = (token >> 1) & 3;          // swizzle key
            bf16x8 bfx = *(const bf16x8*)&xnb[token][(quad ^ vtk) * 8];
            f32x4 zz = { 0.f, 0.f, 0.f, 0.f };
            if (token >= qbase && token < qbase + 128) {
                int tq = token - qbase;
#pragma unroll
                for (int mt = 0; mt < 2; mt++) {
                    f32x4 z = __builtin_amdgcn_mfma_f32_16x16x32_bf16(wfr[mt], bfx, zz, 0, 0, 0);
                    uint2 u; u.x = pack2bf(z[0], z[1]); u.y = pack2bf(z[2], z[3]);
                    int lc = 2 * mt + (quad >> 1);
                    *(uint2*)&Qb[tq][(lc ^ vtk) * 8 + (quad & 1) * 4] = u;
                }
            }
#pragma unroll
            for (int mt = 0; mt < 2; mt++) {
                f32x4 z = __builtin_amdgcn_mfma_f32_16x16x32_bf16(wfr[2 + mt], bfx, zz, 0, 0, 0);
                uint2 u; u.x = pack2bf(z[0], z[1]); u.y = pack2bf(z[2], z[3]);
                *(uint2*)&Kb[token][mt * 16 + quad * 4] = u;
            }
            int jinv = (token & ~63) + (token & 15) * 4 + ((token >> 4) & 3);
#pragma unroll
            for (int mt = 0; mt < 2; mt++) {
                f32x4 z = __builtin_amdgcn_mfma_f32_16x16x32_bf16(wfr[4 + mt], bfx, zz, 0, 0, 0);
#pragma unroll
                for (int r = 0; r < 4; r++)
                    Vt[mt * 16 + quad * 4 + r][jinv] = f2bf(z[r]);
            }
        }
        __syncthreads();

        // V fragments: invariant across strips -> hoist to registers
        bf16x8 vfr0[8], vfr1[8];
#pragma unroll
        for (int c = 0; c < 4; c++)
#pragma unroll
            for (int k2 = 0; k2 < 2; k2++) {
                vfr0[c * 2 + k2] = *(const bf16x8*)&Vt[col][c * 64 + k2 * 32 + quad * 8];
                vfr1[c * 2 + k2] = *(const bf16x8*)&Vt[16 + col][c * 64 + k2 * 32 + quad * 8];
            }

        float w0 = w2[2 * h], w1 = w2[2 * h + 1];   // already * log2e
        bf16x8 wof0 = *(const bf16x8*)(woutb + (size_t)col * 256 + h * 32 + quad * 8);
        bf16x8 wof1 = *(const bf16x8*)(woutb + (size_t)(16 + col) * 256 + h * 32 + quad * 8);
        unsigned int qp1 = quad == 0 ? pack2bf(-w0, -w1) : 0u;

        // ---- 2 strips of 16 query rows per wave ----
#pragma unroll
        for (int si = 0; si < 2; si++) {
            int trow = wave * 32 + si * 16 + col;      // row within 128-window
            bf16x8 qa = *(const bf16x8*)&Qb[trow][(quad ^ ((trow >> 1) & 3)) * 8];
            float2 pm = pf[qbase + trow];
            unsigned int qp0 = quad == 0 ? pack2bf(2.0f * w0 * pm.x, 2.0f * w1 * pm.y) : 0u;
            bf16x8 qe;
            qe[0] = (short)(qp0 & 0xffffu); qe[1] = (short)(qp0 >> 16);
            qe[2] = (short)(qp1 & 0xffffu); qe[3] = (short)(qp1 >> 16);
            qe[4] = 0; qe[5] = 0; qe[6] = 0; qe[7] = 0;

            f32x4 acc[16];
#pragma unroll
            for (int nt = 0; nt < 16; nt++) {
                bf16x8 kb = *(const bf16x8*)&Kb[nt * 16 + col][quad * 8];
                f32x4 z = { 0.f, 0.f, 0.f, 0.f };
                z = __builtin_amdgcn_mfma_f32_16x16x32_bf16(qa, kb, z, 0, 0, 0);
                acc[nt] = __builtin_amdgcn_mfma_f32_16x16x32_bf16(qe, keext[nt], z, 0, 0, 0);
            }

            // scores in log2 domain -> hardware exp2
            float rsum[4] = { 0.f, 0.f, 0.f, 0.f };
            f32x4 o0 = { 0.f, 0.f, 0.f, 0.f }, o1 = { 0.f, 0.f, 0.f, 0.f };
#pragma unroll
            for (int c = 0; c < 4; c++) {
#pragma unroll
                for (int r = 0; r < 4; r++) {
                    float e0 = __builtin_amdgcn_exp2f(acc[c * 4 + 0][r]);
                    float e1 = __builtin_amdgcn_exp2f(acc[c * 4 + 1][r]);
                    float e2 = __builtin_amdgcn_exp2f(acc[c * 4 + 2][r]);
                    float e3 = __builtin_amdgcn_exp2f(acc[c * 4 + 3][r]);
                    rsum[r] += (e0 + e1) + (e2 + e3);
                    uint2 pk;
                    pk.x = pack2bf(e0, e1);
                    pk.y = pack2bf(e2, e3);
                    *(uint2*)&Pst[wave][quad * 4 + r][col * 4] = pk;  // kloc = col*4+t
                }
#pragma unroll
                for (int k2 = 0; k2 < 2; k2++) {
                    bf16x8 pa = *(const bf16x8*)&Pst[wave][col][k2 * 32 + quad * 8];
                    o0 = __builtin_amdgcn_mfma_f32_16x16x32_bf16(pa, vfr0[c * 2 + k2], o0, 0, 0, 0);
                    o1 = __builtin_amdgcn_mfma_f32_16x16x32_bf16(pa, vfr1[c * 2 + k2], o1, 0, 0, 0);
                }
            }

            // scale by 1/sum, stage O strip, out-proj accumulate
#pragma unroll
            for (int r = 0; r < 4; r++) {
                float su = rsum[r];
                su += __shfl_xor(su, 1); su += __shfl_xor(su, 2);
                su += __shfl_xor(su, 4); su += __shfl_xor(su, 8);
                float rl = __builtin_amdgcn_rcpf(su);
                Pst[wave][quad * 4 + r][col]      = f2bf(o0[r] * rl);
                Pst[wave][quad * 4 + r][col + 16] = f2bf(o1[r] * rl);
            }
            bf16x8 af = *(const bf16x8*)&Pst[wave][col][quad * 8];
            aggr0[si] = __builtin_amdgcn_mfma_f32_16x16x32_bf16(af, wof0, aggr0[si], 0, 0, 0);
            aggr1[si] = __builtin_amdgcn_mfma_f32_16x16x32_bf16(af, wof1, aggr1[si], 0, 0, 0);
        }
    }

    // ---- epilogue: + b_out + residual, LN2, FFN, residual, scatter store ----
    bf16x8 w1f[2], w2f[2];
#pragma unroll
    for (int ct = 0; ct < 2; ct++) {
        w1f[ct] = *(const bf16x8*)(ff1b + (ct * 16 + col) * 32 + quad * 8);
        w2f[ct] = *(const bf16x8*)(ff2b + (ct * 16 + col) * 32 + quad * 8);
    }
    float bo0 = b_out[col], bo1 = b_out[col + 16];
    float g20 = g2[col], g21 = g2[col + 16], be20 = be2[col], be21 = be2[col + 16];
    float fb10 = ffb1[col], fb11 = ffb1[col + 16];
    float fb20 = ffb2[col], fb21 = ffb2[col + 16];

#pragma unroll
    for (int si = 0; si < 2; si++) {
        int rloc = qbase + wave * 32 + si * 16;   // sorted-local row base
        f32x4 a0 = aggr0[si], a1 = aggr1[si];
        int trow[4];
#pragma unroll
        for (int r = 0; r < 4; r++) trow[r] = (int)order[b * 256 + rloc + quad * 4 + r];

#pragma unroll
        for (int r = 0; r < 4; r++) {
            a0[r] += x[(size_t)trow[r] * 32 + col] + bo0;
            a1[r] += x[(size_t)trow[r] * 32 + 16 + col] + bo1;
        }

        f32x4 xn0, xn1;
#pragma unroll
        for (int r = 0; r < 4; r++) {
            float s = a0[r] + a1[r];
            s += __shfl_xor(s, 1); s += __shfl_xor(s, 2); s += __shfl_xor(s, 4); s += __shfl_xor(s, 8);
            float mu = s * (1.0f / 32.0f);
            float c0 = a0[r] - mu, c1 = a1[r] - mu;
            float v = c0 * c0 + c1 * c1;
            v += __shfl_xor(v, 1); v += __shfl_xor(v, 2); v += __shfl_xor(v, 4); v += __shfl_xor(v, 8);
            float rstd = rsqrtf(v * (1.0f / 32.0f) + 1e-5f);
            xn0[r] = c0 * rstd * g20 + be20;
            xn1[r] = c1 * rstd * g21 + be21;
        }

#pragma unroll
        for (int r = 0; r < 4; r++) {
            Pst[wave][quad * 4 + r][col]      = f2bf(xn0[r]);
            Pst[wave][quad * 4 + r][col + 16] = f2bf(xn1[r]);
        }
        bf16x8 af1 = *(const bf16x8*)&Pst[wave][col][quad * 8];
        f32x4 z = { 0.f, 0.f, 0.f, 0.f };
        f32x4 h0 = __builtin_amdgcn_mfma_f32_16x16x32_bf16(af1, w1f[0], z, 0, 0, 0);
        f32x4 h1 = __builtin_amdgcn_mfma_f32_16x16x32_bf16(af1, w1f[1], z, 0, 0, 0);
#pragma unroll
        for (int r = 0; r < 4; r++) {
            h0[r] = fmaxf(h0[r] + fb10, 0.f);
            h1[r] = fmaxf(h1[r] + fb11, 0.f);
        }

#pragma unroll
        for (int r = 0; r < 4; r++) {
            Pst[wave][quad * 4 + r][col]      = f2bf(h0[r]);
            Pst[wave][quad * 4 + r][col + 16] = f2bf(h1[r]);
        }
        bf16x8 af2 = *(const bf16x8*)&Pst[wave][col][quad * 8];
        f32x4 f0 = __builtin_amdgcn_mfma_f32_16x16x32_bf16(af2, w2f[0], z, 0, 0, 0);
        f32x4 f1 = __builtin_amdgcn_mfma_f32_16x16x32_bf16(af2, w2f[1], z, 0, 0, 0);

#pragma unroll
        for (int r = 0; r < 4; r++) {
            out[(size_t)trow[r] * 32 + col]      = a0[r] + f0[r] + fb20;
            out[(size_t)trow[r] * 32 + 16 + col] = a1[r] + f1[r] + fb21;
        }
    }
}

extern "C" void kernel_launch(void* const* d_in, const int* in_sizes, int n_in,
                              void* d_out, int out_size, void* d_ws, size_t ws_size,
                              hipStream_t stream) {
    (void)in_sizes; (void)n_in; (void)out_size; (void)ws_size;
    const float* x      = (const float*)d_in[0];
    const float* coords = (const float*)d_in[1];
    const float* wq     = (const float*)d_in[2];
    const float* wk     = (const float*)d_in[3];
    const float* wv     = (const float*)d_in[4];
    const float* w_rpe  = (const float*)d_in[5];
    const float* w_out  = (const float*)d_in[6];
    const float* b_out  = (const float*)d_in[7];
    const float* g1     = (const float*)d_in[8];
    const float* be1    = (const float*)d_in[9];
    const float* g2     = (const float*)d_in[10];
    const float* be2    = (const float*)d_in[11];
    const float* ffw1   = (const float*)d_in[12];
    const float* ffb1   = (const float*)d_in[13];
    const float* ffw2   = (const float*)d_in[14];
    const float* ffb2   = (const float*)d_in[15];
    float* out = (float*)d_out;

    char* ws = (char*)d_ws;
    unsigned int* hist2d  = (unsigned int*)(ws);                     // 256 KB
    unsigned int* lstart  = (unsigned int*)(ws + 256 * 1024);        // 256 KB
    unsigned int* locmemb = (unsigned int*)(ws + 512 * 1024);        // 256 KB
    unsigned int* keyarr  = (unsigned int*)(ws + 768 * 1024);        // 256 KB
    unsigned int* order   = (unsigned int*)(ws + 1024 * 1024);       // 256 KB
    float*        w2      = (float*)(ws + 1280 * 1024);              // 16 f32
    unsigned short* wqkvb = (unsigned short*)(ws + 1536 * 1024);     // 48 KB
    unsigned short* woutb = wqkvb + 24576;
    unsigned short* ff1b  = woutb + 8192;
    unsigned short* ff2b  = ff1b + 1024;

    kprep  <<<256, 256, 0, stream>>>(coords, wq, wk, wv, w_out, ffw1, ffw2, w_rpe,
                                     hist2d, lstart, locmemb, keyarr,
                                     wqkvb, woutb, ff1b, ff2b, w2);
    kbucket<<<256, 256, 0, stream>>>(hist2d, lstart, locmemb, keyarr, order);
    kattn  <<<512, 256, 0, stream>>>(x, g1, be1, wqkvb, order, coords, w2,
                                     woutb, b_out, g2, be2,
                                     ff1b, ffb1, ff2b, ffb2, out);
}

// Round 5
// 175.279 us; speedup vs baseline: 2.0523x; 1.0852x over previous
//
#include <hip/hip_runtime.h>
#include <hip/hip_bf16.h>

#define DEV __device__ __forceinline__

typedef __attribute__((ext_vector_type(8))) short bf16x8;
typedef __attribute__((ext_vector_type(4))) float f32x4;

// N=65536 tokens, 8 heads, head dim 32, feature dim 256, block 256
static constexpr float QSCALE = 0.17677669529663687f; // 1/sqrt(32)
static constexpr float LOG2E  = 1.4426950408889634f;

DEV unsigned short f2bf(float f) {
    union { float f; unsigned int u; } a; a.f = f;
    unsigned int r = (a.u + 0x7fffu + ((a.u >> 16) & 1u)) >> 16; // RNE
    return (unsigned short)r;
}
DEV unsigned int pack2bf(float lo, float hi) {   // v_cvt_pk_bf16_f32 on gfx950
    float2 t; t.x = lo; t.y = hi;
    __hip_bfloat162 h = __float22bfloat162_rn(t);
    unsigned int u; __builtin_memcpy(&u, &h, 4);
    return u;
}
DEV unsigned short f2bf1(float f) {              // 1 VALU (cvt_pk, keep low half)
    return (unsigned short)(pack2bf(f, 0.f) & 0xffffu);
}

// ---------------- pre-chain, 2 dispatches ----------------
// K1: block-local counting sort + keyarr + weight bf16 prep + w2.
// hseg[k][b] packs (local_excl_off << 16) | count -- one gather in K2 not two.
__global__ __launch_bounds__(256) void kprep(
    const float* __restrict__ coords,
    const float* __restrict__ wq, const float* __restrict__ wk,
    const float* __restrict__ wv, const float* __restrict__ w_out,
    const float* __restrict__ ff1, const float* __restrict__ ff2,
    const float* __restrict__ w_rpe,
    unsigned int* __restrict__ hseg,        // [256 kblocks][256 buckets] packed
    unsigned int* __restrict__ locmemb,     // [256 kblocks][256] bucket-grouped ids
    unsigned int* __restrict__ keyarr,      // [65536] float bits of coords[:,0]
    unsigned short* wqkvb, unsigned short* woutb,
    unsigned short* ff1b, unsigned short* ff2b, float* w2)
{
    __shared__ unsigned int lhist[256];
    __shared__ unsigned int s[256];
    __shared__ unsigned int loff[256];
    __shared__ float part[4];
    int tid = threadIdx.x;
    int g = blockIdx.x * 256 + tid;

    lhist[tid] = 0u;
    float v = coords[(size_t)g * 3];
    keyarr[g] = __float_as_uint(v);          // keys >= 0 -> bit compare works
    int b8 = (int)(v * 256.0f);
    b8 = b8 < 0 ? 0 : (b8 > 255 ? 255 : b8);
    __syncthreads();
    unsigned int myl = atomicAdd(&lhist[b8], 1u);

    // independent work: weight conversion and w2
    if (g < 34816) {
        int i = g;
        if (i < 8192)        wqkvb[i] = f2bf(wq[i] * (QSCALE * LOG2E));
        else if (i < 16384)  wqkvb[i] = f2bf(wk[i - 8192]);
        else if (i < 24576)  wqkvb[i] = f2bf(wv[i - 16384]);
        else if (i < 32768)  woutb[i - 24576] = f2bf(w_out[i - 24576]);
        else if (i < 33792)  ff1b[i - 32768] = f2bf(ff1[i - 32768]);
        else                 ff2b[i - 33792] = f2bf(ff2[i - 33792]);
    }
    if (blockIdx.x >= 240) {                 // 16 blocks: w2[p], p = h*2 + c
        int p = blockIdx.x - 240;
        int h = p >> 1, c = p & 1;
        int d = tid >> 3, j = tid & 7;
        float w = w_rpe[(h * 32 + d) * 16 + c * 8 + j];
        float w2v = w * w;
        for (int m = 32; m >= 1; m >>= 1) w2v += __shfl_xor(w2v, m);
        if ((tid & 63) == 0) part[tid >> 6] = w2v;
        __syncthreads();
        if (tid == 0) w2[p] = (part[0] + part[1] + part[2] + part[3]) * (1.0f / 256.0f) * LOG2E;
    }
    __syncthreads();

    // block-local exclusive scan of bucket counts
    unsigned int cnt = lhist[tid];
    s[tid] = cnt; __syncthreads();
    for (int off = 1; off < 256; off <<= 1) {
        unsigned int t = (tid >= off) ? s[tid - off] : 0u;
        __syncthreads();
        s[tid] += t;
        __syncthreads();
    }
    unsigned int lexcl = s[tid] - cnt;
    loff[tid] = lexcl;
    hseg[blockIdx.x * 256 + tid] = (lexcl << 16) | cnt;   // coalesced, packed
    __syncthreads();

    // block-local bucket-grouped scatter
    locmemb[blockIdx.x * 256 + loff[b8] + myl] = (unsigned int)g;
}

// K2: one block per bucket, 512 threads (R4 lesson: 256-thread version ran at
// 1 wave/SIMD -- every L2/HBM latency fully exposed; 512 threads doubles the
// latency hiding in the gather/rank phases).
__global__ __launch_bounds__(512) void kbucket(
    const unsigned int* __restrict__ hseg,
    const unsigned int* __restrict__ locmemb,
    const unsigned int* __restrict__ keyarr,
    unsigned int* __restrict__ order)
{
    __shared__ unsigned int s[256];
    __shared__ unsigned int csum[512];
    __shared__ unsigned int mkey[512];
    __shared__ unsigned int midx[512];
    int tid = threadIdx.x;
    int b = blockIdx.x;
    int t8 = tid & 255, hi = tid >> 8;

    // bucket totals: column-sum of hseg counts, k-range split across thread halves
    unsigned int tot = 0;
#pragma unroll 16
    for (int k = 0; k < 128; k++) tot += hseg[(hi * 128 + k) * 256 + t8] & 0xffffu;
    csum[tid] = tot;
    __syncthreads();
    if (tid < 256) s[tid] = csum[tid] + csum[tid + 256];
    __syncthreads();

    // inclusive scan over 256 bucket totals -> global start of bucket b
    for (int off = 1; off < 256; off <<= 1) {
        unsigned int t = 0;
        if (tid < 256 && tid >= off) t = s[tid - off];
        __syncthreads();
        if (tid < 256) s[tid] += t;
        __syncthreads();
    }
    unsigned int start = (b == 0) ? 0u : s[b - 1];
    __syncthreads();

    // this bucket's segment in each kblock: one packed gather
    unsigned int segcnt = 0, segoff = 0;
    if (tid < 256) {
        unsigned int pk = hseg[tid * 256 + b];
        segcnt = pk & 0xffffu;
        segoff = pk >> 16;
    }
    __syncthreads();
    s[t8] = 0u;
    __syncthreads();
    if (tid < 256) s[tid] = segcnt;
    __syncthreads();
    for (int off = 1; off < 256; off <<= 1) {
        unsigned int t = 0;
        if (tid < 256 && tid >= off) t = s[tid - off];
        __syncthreads();
        if (tid < 256) s[tid] += t;
        __syncthreads();
    }
    unsigned int dst = (tid < 256) ? s[tid] - segcnt : 0u;
    unsigned int cntb = s[255];
    if (cntb > 512u) cntb = 512u;
    __syncthreads();

    // copy member ids, then batch-gather keys
    if (tid < 256) {
        for (unsigned int j = 0; j < segcnt; j++) {
            unsigned int p = dst + j;
            if (p < 512u) midx[p] = locmemb[tid * 256 + segoff + j];
        }
    }
    __syncthreads();
    for (unsigned int p = tid; p < cntb; p += 512) mkey[p] = keyarr[midx[p]];
    __syncthreads();

    // stable rank via lockstep-broadcast compare (cnt ~256, one m per thread)
    for (unsigned int m = tid; m < cntb; m += 512) {
        unsigned int km = mkey[m], im = midx[m];
        unsigned int r = 0;
        for (unsigned int j = 0; j < cntb; j++) {
            unsigned int kj = mkey[j];
            r += (kj < km || (kj == km && midx[j] < im)) ? 1u : 0u;
        }
        order[start + r] = im;
    }
}

// ---------------- fully fused: LN1 + QKV + attention(8 heads) + out-proj +
// residual + LN2 + FFN + residual, per (bucket, query-half) block ----------------
// R5 changes vs R4 (kattn only):
//  - Kb unpadded [256][32] with chunk-XOR swizzle (same pattern as Qb; reads stay
//    2-way aliased = free per m136) -> -4 KB LDS.
//  - Pst double-buffered by chunk parity: breaks the WAR hazard that serialized
//    {exp2 -> pack -> LDS write -> wait -> read -> PV MFMA} x4 per strip; the
//    unrolled scheduler can now overlap exp(c+1) with PV(c).
//  - V/O staging bf16 converts via single v_cvt_pk (f2bf1) instead of 5-op f2bf.
// LDS: xnb 16384 + Qb 8192 + Kb 16384 + Vt 16896 + kext 2048 + pf 2048
//      + Pst 18432 = 80384 B <= 81920 -> still 2 blocks/CU.
__global__ __launch_bounds__(256, 2) void kattn(
    const float* __restrict__ x, const float* __restrict__ g1, const float* __restrict__ be1,
    const unsigned short* __restrict__ wqkvb,
    const unsigned int* __restrict__ order, const float* __restrict__ coords,
    const float* __restrict__ w2,
    const unsigned short* __restrict__ woutb, const float* __restrict__ b_out,
    const float* __restrict__ g2, const float* __restrict__ be2,
    const unsigned short* __restrict__ ff1b, const float* __restrict__ ffb1,
    const unsigned short* __restrict__ ff2b, const float* __restrict__ ffb2,
    float* __restrict__ out)
{
    __shared__ unsigned short xnb[256][32];      // 16384 B  LN'd x, swizzled chunks
    __shared__ unsigned short Qb[128][32];       //  8192 B  this half's Q, swizzled
    __shared__ unsigned short Kb[256][32];       // 16384 B  swizzled chunks
    __shared__ unsigned short Vt[32][264];       // 16896 B  [feature][permuted token]
    __shared__ unsigned short kext[256][4];      //  2048 B  {a, b, a^2, b^2} bf16
    __shared__ float2 pf[256];                   //  2048 B  f32 coords for Q side
    __shared__ unsigned short Pst[4][2][16][72]; // 18432 B  per-wave double-buffered P

    int bh = blockIdx.x;
    int b = (bh & 7) * 32 + ((bh >> 3) & 31);   // bucket; both halves share bh%8 (XCD)
    int qbase = (bh >> 8) * 128;                // query-row window base (0 or 128)
    int tid = threadIdx.x, wave = tid >> 6, lane = tid & 63;
    int col = lane & 15, quad = lane >> 4;

    // ---- stage A: gather x row, LN1 -> xnb (swizzled); coords -> kext/pf ----
    {
        int t = tid;
        int tok = (int)order[b * 256 + t];
        float a = coords[tok * 3 + 1], bb = coords[tok * 3 + 2];
        pf[t] = make_float2(a, bb);
        uint2 kv;
        kv.x = pack2bf(a, bb);
        kv.y = pack2bf(a * a, bb * bb);
        *(uint2*)&kext[t][0] = kv;

        float xv[32];
        const float4* xr = (const float4*)(x + (size_t)tok * 32);
#pragma unroll
        for (int q4 = 0; q4 < 8; q4++) {
            float4 v4 = xr[q4];
            xv[q4 * 4 + 0] = v4.x; xv[q4 * 4 + 1] = v4.y; xv[q4 * 4 + 2] = v4.z; xv[q4 * 4 + 3] = v4.w;
        }
        float mu = 0.f;
#pragma unroll
        for (int d = 0; d < 32; d++) mu += xv[d];
        mu *= (1.0f / 32.0f);
        float var = 0.f;
#pragma unroll
        for (int d = 0; d < 32; d++) { float c = xv[d] - mu; var += c * c; }
        var *= (1.0f / 32.0f);
        float rstd = rsqrtf(var + 1e-5f);
        unsigned int pk[16];
#pragma unroll
        for (int w = 0; w < 16; w++) {
            float a2 = (xv[2 * w] - mu) * rstd * g1[2 * w] + be1[2 * w];
            float b2 = (xv[2 * w + 1] - mu) * rstd * g1[2 * w + 1] + be1[2 * w + 1];
            pk[w] = pack2bf(a2, b2);
        }
        int v = (t >> 1) & 3;                    // chunk swizzle key
        uint4* dst = (uint4*)&xnb[t][0];
#pragma unroll
        for (int w4 = 0; w4 < 4; w4++) {
            uint4 v4; v4.x = pk[w4*4]; v4.y = pk[w4*4+1]; v4.z = pk[w4*4+2]; v4.w = pk[w4*4+3];
            dst[w4 ^ v] = v4;                    // logical chunk w4 -> physical w4^v
        }
    }
    __syncthreads();

    // extended-K fragments: head-independent {a, b, a^2, b^2} -> hoist once
    bf16x8 keext[16];
#pragma unroll
    for (int nt = 0; nt < 16; nt++) {
        uint2 kv = *(const uint2*)&kext[nt * 16 + col][0];
        unsigned int a0 = quad == 0 ? kv.x : 0u;
        unsigned int a1 = quad == 0 ? kv.y : 0u;
        bf16x8 f;
        f[0] = (short)(a0 & 0xffffu); f[1] = (short)(a0 >> 16);
        f[2] = (short)(a1 & 0xffffu); f[3] = (short)(a1 >> 16);
        f[4] = 0; f[5] = 0; f[6] = 0; f[7] = 0;
        keext[nt] = f;
    }

    // out-proj accumulators: 2 strips x 32 out-features, f32, live across heads
    f32x4 aggr0[2], aggr1[2];
#pragma unroll
    for (int si = 0; si < 2; si++) {
        aggr0[si] = (f32x4){ 0.f, 0.f, 0.f, 0.f };
        aggr1[si] = (f32x4){ 0.f, 0.f, 0.f, 0.f };
    }

#pragma unroll 1
    for (int h = 0; h < 8; h++) {
        // weight A-fragments for this head (global 16 B loads, L2-resident)
        bf16x8 wfr[6];
#pragma unroll
        for (int g = 0; g < 3; g++)
#pragma unroll
            for (int mt = 0; mt < 2; mt++)
                wfr[g * 2 + mt] = *(const bf16x8*)(wqkvb + (size_t)(g * 256 + h * 32 + mt * 16 + col) * 32 + quad * 8);

        if (h) __syncthreads();                  // prev head's strip readers done

        // ---- staging B: K/V for all 256 tokens, Q for this half's 128 rows ----
#pragma unroll
        for (int si = 0; si < 4; si++) {
            int token = wave * 64 + si * 16 + col;
            int vtk = (token >> 1) & 3;          // swizzle key
            bf16x8 bfx = *(const bf16x8*)&xnb[token][(quad ^ vtk) * 8];
            f32x4 zz = { 0.f, 0.f, 0.f, 0.f };
            if (token >= qbase && token < qbase + 128) {
                int tq = token - qbase;
#pragma unroll
                for (int mt = 0; mt < 2; mt++) {
                    f32x4 z = __builtin_amdgcn_mfma_f32_16x16x32_bf16(wfr[mt], bfx, zz, 0, 0, 0);
                    uint2 u; u.x = pack2bf(z[0], z[1]); u.y = pack2bf(z[2], z[3]);
                    int lc = 2 * mt + (quad >> 1);
                    *(uint2*)&Qb[tq][(lc ^ vtk) * 8 + (quad & 1) * 4] = u;
                }
            }
#pragma unroll
            for (int mt = 0; mt < 2; mt++) {
                f32x4 z = __builtin_amdgcn_mfma_f32_16x16x32_bf16(wfr[2 + mt], bfx, zz, 0, 0, 0);
                uint2 u; u.x = pack2bf(z[0], z[1]); u.y = pack2bf(z[2], z[3]);
                int lc = 2 * mt + (quad >> 1);
                *(uint2*)&Kb[token][(lc ^ vtk) * 8 + (quad & 1) * 4] = u;   // swizzled
            }
            int jinv = (token & ~63) + (token & 15) * 4 + ((token >> 4) & 3);
#pragma unroll
            for (int mt = 0; mt < 2; mt++) {
                f32x4 z = __builtin_amdgcn_mfma_f32_16x16x32_bf16(wfr[4 + mt], bfx, zz, 0, 0, 0);
#pragma unroll
                for (int r = 0; r < 4; r++)
                    Vt[mt * 16 + quad * 4 + r][jinv] = f2bf1(z[r]);
            }
        }
        __syncthreads();

        // V fragments: invariant across strips -> hoist to registers
        bf16x8 vfr0[8], vfr1[8];
#pragma unroll
        for (int c = 0; c < 4; c++)
#pragma unroll
            for (int k2 = 0; k2 < 2; k2++) {
                vfr0[c * 2 + k2] = *(const bf16x8*)&Vt[col][c * 64 + k2 * 32 + quad * 8];
                vfr1[c * 2 + k2] = *(const bf16x8*)&Vt[16 + col][c * 64 + k2 * 32 + quad * 8];
            }

        float w0 = w2[2 * h], w1 = w2[2 * h + 1];   // already * log2e
        bf16x8 wof0 = *(const bf16x8*)(woutb + (size_t)col * 256 + h * 32 + quad * 8);
        bf16x8 wof1 = *(const bf16x8*)(woutb + (size_t)(16 + col) * 256 + h * 32 + quad * 8);
        unsigned int qp1 = quad == 0 ? pack2bf(-w0, -w1) : 0u;

        // Kb read swizzle key: row = nt*16+col -> ((row>>1)&3) == ((col>>1)&3)
        int kswz = (quad ^ ((col >> 1) & 3)) * 8;

        // ---- 2 strips of 16 query rows per wave ----
#pragma unroll
        for (int si = 0; si < 2; si++) {
            int trow = wave * 32 + si * 16 + col;      // row within 128-window
            bf16x8 qa = *(const bf16x8*)&Qb[trow][(quad ^ ((trow >> 1) & 3)) * 8];
            float2 pm = pf[qbase + trow];
            unsigned int qp0 = quad == 0 ? pack2bf(2.0f * w0 * pm.x, 2.0f * w1 * pm.y) : 0u;
            bf16x8 qe;
            qe[0] = (short)(qp0 & 0xffffu); qe[1] = (short)(qp0 >> 16);
            qe[2] = (short)(qp1 & 0xffffu); qe[3] = (short)(qp1 >> 16);
            qe[4] = 0; qe[5] = 0; qe[6] = 0; qe[7] = 0;

            f32x4 acc[16];
#pragma unroll
            for (int nt = 0; nt < 16; nt++) {
                bf16x8 kb = *(const bf16x8*)&Kb[nt * 16 + col][kswz];
                f32x4 z = { 0.f, 0.f, 0.f, 0.f };
                z = __builtin_amdgcn_mfma_f32_16x16x32_bf16(qa, kb, z, 0, 0, 0);
                acc[nt] = __builtin_amdgcn_mfma_f32_16x16x32_bf16(qe, keext[nt], z, 0, 0, 0);
            }

            // scores in log2 domain -> hardware exp2; P double-buffered by c-parity
            float rsum[4] = { 0.f, 0.f, 0.f, 0.f };
            f32x4 o0 = { 0.f, 0.f, 0.f, 0.f }, o1 = { 0.f, 0.f, 0.f, 0.f };
#pragma unroll
            for (int c = 0; c < 4; c++) {
#pragma unroll
                for (int r = 0; r < 4; r++) {
                    float e0 = __builtin_amdgcn_exp2f(acc[c * 4 + 0][r]);
                    float e1 = __builtin_amdgcn_exp2f(acc[c * 4 + 1][r]);
                    float e2 = __builtin_amdgcn_exp2f(acc[c * 4 + 2][r]);
                    float e3 = __builtin_amdgcn_exp2f(acc[c * 4 + 3][r]);
                    rsum[r] += (e0 + e1) + (e2 + e3);
                    uint2 pk;
                    pk.x = pack2bf(e0, e1);
                    pk.y = pack2bf(e2, e3);
                    *(uint2*)&Pst[wave][c & 1][quad * 4 + r][col * 4] = pk;  // kloc = col*4+t
                }
#pragma unroll
                for (int k2 = 0; k2 < 2; k2++) {
                    bf16x8 pa = *(const bf16x8*)&Pst[wave][c & 1][col][k2 * 32 + quad * 8];
                    o0 = __builtin_amdgcn_mfma_f32_16x16x32_bf16(pa, vfr0[c * 2 + k2], o0, 0, 0, 0);
                    o1 = __builtin_amdgcn_mfma_f32_16x16x32_bf16(pa, vfr1[c * 2 + k2], o1, 0, 0, 0);
                }
            }

            // scale by 1/sum, stage O strip, out-proj accumulate
#pragma unroll
            for (int r = 0; r < 4; r++) {
                float su = rsum[r];
                su += __shfl_xor(su, 1); su += __shfl_xor(su, 2);
                su += __shfl_xor(su, 4); su += __shfl_xor(su, 8);
                float rl = __builtin_amdgcn_rcpf(su);
                Pst[wave][0][quad * 4 + r][col]      = f2bf1(o0[r] * rl);
                Pst[wave][0][quad * 4 + r][col + 16] = f2bf1(o1[r] * rl);
            }
            bf16x8 af = *(const bf16x8*)&Pst[wave][0][col][quad * 8];
            aggr0[si] = __builtin_amdgcn_mfma_f32_16x16x32_bf16(af, wof0, aggr0[si], 0, 0, 0);
            aggr1[si] = __builtin_amdgcn_mfma_f32_16x16x32_bf16(af, wof1, aggr1[si], 0, 0, 0);
        }
    }

    // ---- epilogue: + b_out + residual, LN2, FFN, residual, scatter store ----
    bf16x8 w1f[2], w2f[2];
#pragma unroll
    for (int ct = 0; ct < 2; ct++) {
        w1f[ct] = *(const bf16x8*)(ff1b + (ct * 16 + col) * 32 + quad * 8);
        w2f[ct] = *(const bf16x8*)(ff2b + (ct * 16 + col) * 32 + quad * 8);
    }
    float bo0 = b_out[col], bo1 = b_out[col + 16];
    float g20 = g2[col], g21 = g2[col + 16], be20 = be2[col], be21 = be2[col + 16];
    float fb10 = ffb1[col], fb11 = ffb1[col + 16];
    float fb20 = ffb2[col], fb21 = ffb2[col + 16];

#pragma unroll
    for (int si = 0; si < 2; si++) {
        int rloc = qbase + wave * 32 + si * 16;   // sorted-local row base
        f32x4 a0 = aggr0[si], a1 = aggr1[si];
        int trow[4];
#pragma unroll
        for (int r = 0; r < 4; r++) trow[r] = (int)order[b * 256 + rloc + quad * 4 + r];

#pragma unroll
        for (int r = 0; r < 4; r++) {
            a0[r] += x[(size_t)trow[r] * 32 + col] + bo0;
            a1[r] += x[(size_t)trow[r] * 32 + 16 + col] + bo1;
        }

        f32x4 xn0, xn1;
#pragma unroll
        for (int r = 0; r < 4; r++) {
            float s = a0[r] + a1[r];
            s += __shfl_xor(s, 1); s += __shfl_xor(s, 2); s += __shfl_xor(s, 4); s += __shfl_xor(s, 8);
            float mu = s * (1.0f / 32.0f);
            float c0 = a0[r] - mu, c1 = a1[r] - mu;
            float v = c0 * c0 + c1 * c1;
            v += __shfl_xor(v, 1); v += __shfl_xor(v, 2); v += __shfl_xor(v, 4); v += __shfl_xor(v, 8);
            float rstd = rsqrtf(v * (1.0f / 32.0f) + 1e-5f);
            xn0[r] = c0 * rstd * g20 + be20;
            xn1[r] = c1 * rstd * g21 + be21;
        }

#pragma unroll
        for (int r = 0; r < 4; r++) {
            Pst[wave][0][quad * 4 + r][col]      = f2bf1(xn0[r]);
            Pst[wave][0][quad * 4 + r][col + 16] = f2bf1(xn1[r]);
        }
        bf16x8 af1 = *(const bf16x8*)&Pst[wave][0][col][quad * 8];
        f32x4 z = { 0.f, 0.f, 0.f, 0.f };
        f32x4 h0 = __builtin_amdgcn_mfma_f32_16x16x32_bf16(af1, w1f[0], z, 0, 0, 0);
        f32x4 h1 = __builtin_amdgcn_mfma_f32_16x16x32_bf16(af1, w1f[1], z, 0, 0, 0);
#pragma unroll
        for (int r = 0; r < 4; r++) {
            h0[r] = fmaxf(h0[r] + fb10, 0.f);
            h1[r] = fmaxf(h1[r] + fb11, 0.f);
        }

#pragma unroll
        for (int r = 0; r < 4; r++) {
            Pst[wave][0][quad * 4 + r][col]      = f2bf1(h0[r]);
            Pst[wave][0][quad * 4 + r][col + 16] = f2bf1(h1[r]);
        }
        bf16x8 af2 = *(const bf16x8*)&Pst[wave][0][col][quad * 8];
        f32x4 f0 = __builtin_amdgcn_mfma_f32_16x16x32_bf16(af2, w2f[0], z, 0, 0, 0);
        f32x4 f1 = __builtin_amdgcn_mfma_f32_16x16x32_bf16(af2, w2f[1], z, 0, 0, 0);

#pragma unroll
        for (int r = 0; r < 4; r++) {
            out[(size_t)trow[r] * 32 + col]      = a0[r] + f0[r] + fb20;
            out[(size_t)trow[r] * 32 + 16 + col] = a1[r] + f1[r] + fb21;
        }
    }
}

extern "C" void kernel_launch(void* const* d_in, const int* in_sizes, int n_in,
                              void* d_out, int out_size, void* d_ws, size_t ws_size,
                              hipStream_t stream) {
    (void)in_sizes; (void)n_in; (void)out_size; (void)ws_size;
    const float* x      = (const float*)d_in[0];
    const float* coords = (const float*)d_in[1];
    const float* wq     = (const float*)d_in[2];
    const float* wk     = (const float*)d_in[3];
    const float* wv     = (const float*)d_in[4];
    const float* w_rpe  = (const float*)d_in[5];
    const float* w_out  = (const float*)d_in[6];
    const float* b_out  = (const float*)d_in[7];
    const float* g1     = (const float*)d_in[8];
    const float* be1    = (const float*)d_in[9];
    const float* g2     = (const float*)d_in[10];
    const float* be2    = (const float*)d_in[11];
    const float* ffw1   = (const float*)d_in[12];
    const float* ffb1   = (const float*)d_in[13];
    const float* ffw2   = (const float*)d_in[14];
    const float* ffb2   = (const float*)d_in[15];
    float* out = (float*)d_out;

    char* ws = (char*)d_ws;
    unsigned int* hseg    = (unsigned int*)(ws);                     // 256 KB
    unsigned int* locmemb = (unsigned int*)(ws + 512 * 1024);        // 256 KB
    unsigned int* keyarr  = (unsigned int*)(ws + 768 * 1024);        // 256 KB
    unsigned int* order   = (unsigned int*)(ws + 1024 * 1024);       // 256 KB
    float*        w2      = (float*)(ws + 1280 * 1024);              // 16 f32
    unsigned short* wqkvb = (unsigned short*)(ws + 1536 * 1024);     // 48 KB
    unsigned short* woutb = wqkvb + 24576;
    unsigned short* ff1b  = woutb + 8192;
    unsigned short* ff2b  = ff1b + 1024;

    kprep  <<<256, 256, 0, stream>>>(coords, wq, wk, wv, w_out, ffw1, ffw2, w_rpe,
                                     hseg, locmemb, keyarr,
                                     wqkvb, woutb, ff1b, ff2b, w2);
    kbucket<<<256, 512, 0, stream>>>(hseg, locmemb, keyarr, order);
    kattn  <<<512, 256, 0, stream>>>(x, g1, be1, wqkvb, order, coords, w2,
                                     woutb, b_out, g2, be2,
                                     ff1b, ffb1, ff2b, ffb2, out);
}